// Round 9
// baseline (736.399 us; speedup 1.0000x reference)
//
#include <hip/hip_runtime.h>
#include <math.h>

#define BB 64
#define DD 512
#define HW 1024
#define NN 20
#define EE 512
#define CIN 520
#define KCN 17            // K chunks of 32 (K padded 520 -> 544)
#define TEMP_F 10.0f

#define OUT_ALANG (BB*DD*HW)            // 33554432
#define OUT_ASCORE (OUT_ALANG + BB*DD)  // 33587200

typedef __bf16 bf16x8 __attribute__((ext_vector_type(8)));
typedef float f32x4 __attribute__((ext_vector_type(4)));

__device__ __forceinline__ unsigned int pack2bf(float a, float b) {
    unsigned int ua = __builtin_bit_cast(unsigned int, a);
    unsigned int ub = __builtin_bit_cast(unsigned int, b);
    ua += 0x7fffu + ((ua >> 16) & 1u);   // RTNE
    ub += 0x7fffu + ((ub >> 16) & 1u);
    return (ua >> 16) | (ub & 0xffff0000u);
}

__device__ __forceinline__ unsigned short bfr(float x) {
    unsigned int u = __builtin_bit_cast(unsigned int, x);
    u += 0x7fffu + ((u >> 16) & 1u);
    return (unsigned short)(u >> 16);
}

__device__ __forceinline__ float bf2f(unsigned short u) {
    unsigned int x = ((unsigned int)u) << 16;
    return __builtin_bit_cast(float, x);
}

// ---------------- Kernel A (fallback only): tile_visu ----------------
__global__ __launch_bounds__(256) void k_tilevisu(const float* __restrict__ fvisu,
                                                  float* __restrict__ tv) {
    int row = blockIdx.x;
    const float4* p = (const float4*)(fvisu + (size_t)row * HW);
    int tid = threadIdx.x;
    float4 v = p[tid];
    float s = v.x + v.y + v.z + v.w;
    #pragma unroll
    for (int off = 32; off; off >>= 1) s += __shfl_down(s, off, 64);
    __shared__ float part[4];
    if ((tid & 63) == 0) part[tid >> 6] = s;
    __syncthreads();
    if (tid == 0) tv[row] = (part[0] + part[1] + part[2] + part[3]) * (1.0f / HW);
}

// ---------------- Kernel X1: fused tile_visu + pack X -> bf16 fragments (float4 loads) ----------------
__global__ __launch_bounds__(512) void k_convert_x(
    const float* __restrict__ fvisu, const float* __restrict__ fcoord,
    unsigned short* __restrict__ Xf, float* __restrict__ tv) {
    int L = blockIdx.x;
    int kc = L % KCN;
    int b  = L / KCN;
    int t = threadIdx.x;
    int co = t >> 7;          // 0..3 (wave-uniform)
    int tl = t & 127;
    int cbase = kc * 32 + co * 8;
    float sums[8];
    #pragma unroll
    for (int j = 0; j < 8; ++j) sums[j] = 0.f;

    #pragma unroll
    for (int i = 0; i < 2; ++i) {
        int p0 = (tl + 128 * i) * 4;
        float4 f4[8];
        #pragma unroll
        for (int j = 0; j < 8; ++j) {
            int c = cbase + j;
            if (c < DD) {
                f4[j] = *(const float4*)&fvisu[((size_t)b * DD + c) * HW + p0];
            } else if (c < CIN) {
                f4[j] = *(const float4*)&fcoord[((size_t)b * 8 + (c - DD)) * HW + p0];
            } else {
                f4[j] = make_float4(0.f, 0.f, 0.f, 0.f);
            }
        }
        #pragma unroll
        for (int j = 0; j < 8; ++j)
            if (cbase + j < DD) sums[j] += f4[j].x + f4[j].y + f4[j].z + f4[j].w;

        size_t base = (((size_t)b * 64 + (p0 >> 4)) * KCN + kc) * 512
                    + (size_t)(co * 16 + (p0 & 15)) * 8;
        #pragma unroll
        for (int i2 = 0; i2 < 4; ++i2) {
            uint4 v;
            v.x = pack2bf(((const float*)&f4[0])[i2], ((const float*)&f4[1])[i2]);
            v.y = pack2bf(((const float*)&f4[2])[i2], ((const float*)&f4[3])[i2]);
            v.z = pack2bf(((const float*)&f4[4])[i2], ((const float*)&f4[5])[i2]);
            v.w = pack2bf(((const float*)&f4[6])[i2], ((const float*)&f4[7])[i2]);
            *(uint4*)&Xf[base + (size_t)i2 * 8] = v;
        }
    }

    #pragma unroll
    for (int j = 0; j < 8; ++j) {
        float s = sums[j];
        #pragma unroll
        for (int off = 32; off; off >>= 1) s += __shfl_down(s, off, 64);
        sums[j] = s;
    }
    __shared__ float red[8][8];
    int w = t >> 6;
    if ((t & 63) == 0) {
        #pragma unroll
        for (int j = 0; j < 8; ++j) red[w][j] = sums[j];
    }
    __syncthreads();
    if (t < 32) {
        int j = t & 7, c2 = t >> 3;
        int c = kc * 32 + c2 * 8 + j;
        if (c < DD) tv[(size_t)b * DD + c] = (red[c2 * 2][j] + red[c2 * 2 + 1][j]) * (1.0f / HW);
    }
}

// ---------------- Kernel X2: merged param converts (Wf | Whi/Wlo | gwT) ----------------
// blocks 0..135: cw -> Wf frags; 136..199: amw -> hi/lo frags; 200..327: gw -> gwT transpose
__global__ __launch_bounds__(256) void k_convert_params(
    const float* __restrict__ cw, unsigned short* __restrict__ Wf,
    const float* __restrict__ amw, unsigned short* __restrict__ Whi,
    unsigned short* __restrict__ Wlo,
    const float* __restrict__ gw, float* __restrict__ gwT) {
    int B0 = blockIdx.x;
    int t = threadIdx.x;
    if (B0 < 136) {
        int frag = B0 * 4 + (t >> 6);   // 0..543
        int l = t & 63;
        int M = frag / KCN, kc = frag % KCN;
        int o = M * 16 + (l & 15);
        int k0 = kc * 32 + (l >> 4) * 8;
        float f[8];
        #pragma unroll
        for (int j = 0; j < 8; ++j) {
            int k = k0 + j;
            f[j] = (k < CIN) ? cw[(size_t)o * CIN + k] : 0.f;
        }
        uint4 v;
        v.x = pack2bf(f[0], f[1]);
        v.y = pack2bf(f[2], f[3]);
        v.z = pack2bf(f[4], f[5]);
        v.w = pack2bf(f[6], f[7]);
        *(uint4*)&Wf[(size_t)frag * 512 + (size_t)l * 8] = v;
    } else if (B0 < 200) {
        int fid = (B0 - 136) * 4 + (t >> 6);    // 0..255
        int l = t & 63;
        int o = (fid >> 4) * 16 + (l & 15);
        int k0 = (fid & 15) * 32 + ((l >> 4) & 3) * 8;
        float hi[8], lo[8];
        #pragma unroll
        for (int j = 0; j < 8; ++j) {
            float x = amw[(size_t)o * DD + k0 + j];
            unsigned short h = bfr(x);
            hi[j] = bf2f(h);
            lo[j] = x - hi[j];
        }
        uint4 vh, vl;
        vh.x = pack2bf(hi[0], hi[1]); vh.y = pack2bf(hi[2], hi[3]);
        vh.z = pack2bf(hi[4], hi[5]); vh.w = pack2bf(hi[6], hi[7]);
        vl.x = pack2bf(lo[0], lo[1]); vl.y = pack2bf(lo[2], lo[3]);
        vl.z = pack2bf(lo[4], lo[5]); vl.w = pack2bf(lo[6], lo[7]);
        *(uint4*)&Whi[(size_t)fid * 512 + (size_t)l * 8] = vh;
        *(uint4*)&Wlo[(size_t)fid * 512 + (size_t)l * 8] = vl;
    } else {
        __shared__ float tile[64][65];
        int bt = B0 - 200;
        int rt = bt & 15, kt = bt >> 4;
        int rl = t >> 4;            // 0..15
        int kl = (t & 15) * 4;      // 0..60
        #pragma unroll
        for (int i = 0; i < 4; ++i) {
            int rr = rl + i * 16;
            float4 v = *(const float4*)&gw[(size_t)(rt * 64 + rr) * DD + kt * 64 + kl];
            tile[rr][kl + 0] = v.x; tile[rr][kl + 1] = v.y;
            tile[rr][kl + 2] = v.z; tile[rr][kl + 3] = v.w;
        }
        __syncthreads();
        #pragma unroll
        for (int i = 0; i < 4; ++i) {
            int kk = rl + i * 16;
            float4 v;
            v.x = tile[kl + 0][kk]; v.y = tile[kl + 1][kk];
            v.z = tile[kl + 2][kk]; v.w = tile[kl + 3][kk];
            *(float4*)&gwT[(size_t)(kt * 64 + kk) * 1024 + rt * 64 + kl] = v;
        }
    }
}

// ---------------- Kernel B: attn_score via MFMA hi/lo + fused softmax/mask + attn_lang ----------------
__global__ __launch_bounds__(256) void k_attnscore(
    const float* __restrict__ fword, const float* __restrict__ cs,
    const float* __restrict__ tv, const unsigned short* __restrict__ Whi,
    const unsigned short* __restrict__ Wlo, const float* __restrict__ amb,
    const float* __restrict__ asw, const float* __restrict__ asb,
    const int* __restrict__ wmask, float* __restrict__ out_ascore,
    float* __restrict__ out_alang) {
    int b = blockIdx.x;
    __shared__ unsigned short uhi[2][16][64][8];   // 32 KB: [mt][ks][lane][j]
    __shared__ unsigned short ulo[2][16][64][8];   // 32 KB
    __shared__ float scoreP[4][32];
    __shared__ float asc_sh[NN];
    __shared__ float msh[NN];
    int t = threadIdx.x;

    {
        int n = t & 31, kq = t >> 5;               // kq: k-range of 64
        float csv = (n < NN) ? cs[b * NN + n] : 0.f;
        const float* fwp = fword + ((size_t)b * NN + (n < NN ? n : 0)) * DD;
        const float* tvp = tv + (size_t)b * DD;
        int mt = n >> 4;
        #pragma unroll
        for (int oc = 0; oc < 8; ++oc) {
            int k = kq * 64 + oc * 8;
            float x[8];
            if (n < NN) {
                float4 f0 = *(const float4*)&fwp[k];
                float4 f1 = *(const float4*)&fwp[k + 4];
                float4 t0 = *(const float4*)&tvp[k];
                float4 t1 = *(const float4*)&tvp[k + 4];
                x[0] = f0.x * t0.x * csv; x[1] = f0.y * t0.y * csv;
                x[2] = f0.z * t0.z * csv; x[3] = f0.w * t0.w * csv;
                x[4] = f1.x * t1.x * csv; x[5] = f1.y * t1.y * csv;
                x[6] = f1.z * t1.z * csv; x[7] = f1.w * t1.w * csv;
            } else {
                #pragma unroll
                for (int j = 0; j < 8; ++j) x[j] = 0.f;
            }
            float h[8], lw[8];
            #pragma unroll
            for (int j = 0; j < 8; ++j) {
                h[j] = bf2f(bfr(x[j]));
                lw[j] = x[j] - h[j];
            }
            int ks = k >> 5;
            int l = (n & 15) + ((k >> 3) & 3) * 16;
            uint4 vh, vl;
            vh.x = pack2bf(h[0], h[1]); vh.y = pack2bf(h[2], h[3]);
            vh.z = pack2bf(h[4], h[5]); vh.w = pack2bf(h[6], h[7]);
            vl.x = pack2bf(lw[0], lw[1]); vl.y = pack2bf(lw[2], lw[3]);
            vl.z = pack2bf(lw[4], lw[5]); vl.w = pack2bf(lw[6], lw[7]);
            *(uint4*)&uhi[mt][ks][l][0] = vh;
            *(uint4*)&ulo[mt][ks][l][0] = vl;
        }
    }
    __syncthreads();

    int w = t >> 6, l = t & 63;
    f32x4 acc[2][4];
    #pragma unroll
    for (int mt = 0; mt < 2; ++mt)
        #pragma unroll
        for (int nt = 0; nt < 4; ++nt) acc[mt][nt] = (f32x4){0.f, 0.f, 0.f, 0.f};

    #pragma unroll 4
    for (int ks = 0; ks < 16; ++ks) {
        bf16x8 ah0 = *(const bf16x8*)&uhi[0][ks][l][0];
        bf16x8 ah1 = *(const bf16x8*)&uhi[1][ks][l][0];
        bf16x8 al0 = *(const bf16x8*)&ulo[0][ks][l][0];
        bf16x8 al1 = *(const bf16x8*)&ulo[1][ks][l][0];
        #pragma unroll
        for (int nt = 0; nt < 4; ++nt) {
            size_t fo = ((size_t)((w * 4 + nt) * 16 + ks)) * 512 + (size_t)l * 8;
            bf16x8 bh = *(const bf16x8*)&Whi[fo];
            bf16x8 bl = *(const bf16x8*)&Wlo[fo];
            acc[0][nt] = __builtin_amdgcn_mfma_f32_16x16x32_bf16(ah0, bh, acc[0][nt], 0, 0, 0);
            acc[0][nt] = __builtin_amdgcn_mfma_f32_16x16x32_bf16(al0, bh, acc[0][nt], 0, 0, 0);
            acc[0][nt] = __builtin_amdgcn_mfma_f32_16x16x32_bf16(ah0, bl, acc[0][nt], 0, 0, 0);
            acc[1][nt] = __builtin_amdgcn_mfma_f32_16x16x32_bf16(ah1, bh, acc[1][nt], 0, 0, 0);
            acc[1][nt] = __builtin_amdgcn_mfma_f32_16x16x32_bf16(al1, bh, acc[1][nt], 0, 0, 0);
            acc[1][nt] = __builtin_amdgcn_mfma_f32_16x16x32_bf16(ah1, bl, acc[1][nt], 0, 0, 0);
        }
    }

    float ambv[4], aswv[4];
    #pragma unroll
    for (int nt = 0; nt < 4; ++nt) {
        int o = (w * 4 + nt) * 16 + (l & 15);
        ambv[nt] = amb[o];
        aswv[nt] = asw[o];
    }
    #pragma unroll
    for (int mt = 0; mt < 2; ++mt) {
        #pragma unroll
        for (int j = 0; j < 4; ++j) {
            float p = 0.f;
            #pragma unroll
            for (int nt = 0; nt < 4; ++nt)
                p += aswv[nt] * tanhf(acc[mt][nt][j] + ambv[nt]);
            #pragma unroll
            for (int off = 1; off < 16; off <<= 1) p += __shfl_xor(p, off, 64);
            if ((l & 15) == 0) scoreP[w][mt * 16 + (l >> 4) * 4 + j] = p;
        }
    }
    __syncthreads();
    if (t < NN) {
        float v = scoreP[0][t] + scoreP[1][t] + scoreP[2][t] + scoreP[3][t] + asb[0];
        out_ascore[b * NN + t] = v;
        asc_sh[t] = v;
    }
    __syncthreads();

    if (t == 0) {
        float s[NN];
        float mx = -1e30f;
        for (int n = 0; n < NN; ++n) { s[n] = asc_sh[n] * TEMP_F; mx = fmaxf(mx, s[n]); }
        float se = 0.f;
        for (int n = 0; n < NN; ++n) { s[n] = expf(s[n] - mx); se += s[n]; }
        int m[NN]; int idx = 0;
        for (int n = 0; n < NN; ++n) m[n] = wmask[b * NN + n];
        m[0] = 0;
        for (int n = 0; n < NN; ++n) idx += m[n];
        m[idx] = 0;
        float tot = 0.f;
        for (int n = 0; n < NN; ++n) { float v = (s[n] / se) * (float)m[n]; msh[n] = v; tot += v; }
        float inv = 1.f / (tot + 1e-8f);
        for (int n = 0; n < NN; ++n) msh[n] *= inv;
    }
    __syncthreads();

    #pragma unroll 2
    for (int d = t; d < DD; d += 256) {
        float a = 0.f;
        #pragma unroll
        for (int n = 0; n < NN; ++n) a += msh[n] * fword[((size_t)b * NN + n) * DD + d];
        out_alang[b * DD + d] = a;
    }
}

// ---------------- Kernel B-legacy (fallback only) ----------------
__global__ __launch_bounds__(256) void k_attnscore_legacy(
    const float* __restrict__ fword, const float* __restrict__ cs,
    const float* __restrict__ tv, const float* __restrict__ amw,
    const float* __restrict__ amb, const float* __restrict__ asw,
    const float* __restrict__ asb, float* __restrict__ out_ascore) {
    int bn = blockIdx.x;
    int b = bn / NN, n = bn % NN;
    __shared__ float u[DD];
    __shared__ float part[4];
    int tid = threadIdx.x;
    float csv = cs[b * NN + n];
    for (int d = tid; d < DD; d += 256)
        u[d] = tv[b * DD + d] * fword[((size_t)b * NN + n) * DD + d] * csv;
    __syncthreads();
    int o = tid;
    const float4* wrow = (const float4*)(amw + (size_t)o * DD);
    const float4* uv = (const float4*)u;
    float dot = 0.f;
    #pragma unroll 4
    for (int i = 0; i < DD / 4; ++i) {
        float4 w4 = wrow[i]; float4 u4 = uv[i];
        dot += w4.x * u4.x + w4.y * u4.y + w4.z * u4.z + w4.w * u4.w;
    }
    float contrib = asw[o] * tanhf(dot + amb[o]);
    #pragma unroll
    for (int off = 32; off; off >>= 1) contrib += __shfl_down(contrib, off, 64);
    if ((tid & 63) == 0) part[tid >> 6] = contrib;
    __syncthreads();
    if (tid == 0) out_ascore[b * NN + n] = part[0] + part[1] + part[2] + part[3] + asb[0];
}

// ---------------- Kernel C (fallback only): mask_softmax + attn_lang + FiLM decode ----------------
__global__ __launch_bounds__(256) void k_lang_film(
    const float* __restrict__ fword, const int* __restrict__ wmask,
    const float* __restrict__ ascore, const float* __restrict__ gw,
    const float* __restrict__ gb, float* __restrict__ out_alang,
    float* __restrict__ ws_film) {
    int b = blockIdx.x >> 2;
    int qd = blockIdx.x & 3;
    __shared__ float ms[NN];
    __shared__ float al[DD];
    int tid = threadIdx.x;
    if (tid == 0) {
        float s[NN];
        float mx = -1e30f;
        for (int n = 0; n < NN; ++n) { s[n] = ascore[b * NN + n] * TEMP_F; mx = fmaxf(mx, s[n]); }
        float se = 0.f;
        for (int n = 0; n < NN; ++n) { s[n] = expf(s[n] - mx); se += s[n]; }
        int m[NN]; int idx = 0;
        for (int n = 0; n < NN; ++n) m[n] = wmask[b * NN + n];
        m[0] = 0;
        for (int n = 0; n < NN; ++n) idx += m[n];
        m[idx] = 0;
        float tot = 0.f;
        for (int n = 0; n < NN; ++n) { float v = (s[n] / se) * (float)m[n]; ms[n] = v; tot += v; }
        float inv = 1.f / (tot + 1e-8f);
        for (int n = 0; n < NN; ++n) ms[n] *= inv;
    }
    __syncthreads();
    for (int d = tid; d < DD; d += 256) {
        float a = 0.f;
        #pragma unroll
        for (int n = 0; n < NN; ++n) a += ms[n] * fword[((size_t)b * NN + n) * DD + d];
        al[d] = a;
        if (qd == 0) out_alang[b * DD + d] = a;
    }
    __syncthreads();
    {
        int r = qd * 256 + tid;
        const float4* grow = (const float4*)(gw + (size_t)r * DD);
        const float4* av = (const float4*)al;
        float dot = 0.f;
        #pragma unroll 4
        for (int i = 0; i < DD / 4; ++i) {
            float4 g4 = grow[i]; float4 a4 = av[i];
            dot += g4.x * a4.x + g4.y * a4.y + g4.z * a4.z + g4.w * a4.w;
        }
        ws_film[b * 2 * EE + r] = tanhf(dot + gb[r]);
    }
}

// ---------------- Kernel C2: film GEMV, coalesced columns, grid BB*4 ----------------
// block (b, q): threads own consecutive output rows r = q*256 + t; gwT[k][r] coalesced.
__global__ __launch_bounds__(256) void k_film(
    const float* __restrict__ alang, const float* __restrict__ gwT,
    const float* __restrict__ gb, float* __restrict__ ws_film) {
    int b = blockIdx.x >> 2;
    int q = blockIdx.x & 3;
    __shared__ float al[DD];
    int t = threadIdx.x;
    al[t] = alang[b * DD + t];
    al[t + 256] = alang[b * DD + t + 256];
    __syncthreads();
    int r = q * 256 + t;
    float acc = 0.f;
    #pragma unroll 8
    for (int k = 0; k < DD; ++k)
        acc += al[k] * gwT[(size_t)k * 1024 + r];
    ws_film[b * 1024 + r] = tanhf(acc + gb[r]);
}

// ---------------- Kernel D: all-register MFMA GEMM, M=128 tile + IN + FiLM + residual ----------------
// grid 256: block (b, ot) = 128 o-chans x 1024 px, 8 waves, wave tile 128x128.
// acc 256 VGPR + A/B dbuf 128. 4 same-b blocks co-resident on one XCD -> Xf[b] single HBM fetch.
__global__ __launch_bounds__(512) void k_gemm_in_film(
    const unsigned short* __restrict__ Xf, const unsigned short* __restrict__ Wf,
    const float* __restrict__ film, float* __restrict__ out) {
    __shared__ float sP[8][128];
    __shared__ float qP[8][128];
    __shared__ float st[128][4];   // mu, rs, gamma, beta
    int L = blockIdx.x;
    int ot = (L >> 3) & 3;                 // 4 o-tiles of 128
    int b  = (L >> 5) * 8 + (L & 7);       // same-b blocks: same XCD, same round
    int t = threadIdx.x;
    int w = t >> 6, l = t & 63;

    const unsigned short* Xw = Xf + ((size_t)b * 64 + w * 8) * (KCN * 512) + (size_t)l * 8;
    const unsigned short* Wb = Wf + (size_t)(ot * 8) * (KCN * 512) + (size_t)l * 8;

    f32x4 acc[8][8];
    #pragma unroll
    for (int m = 0; m < 8; ++m)
        #pragma unroll
        for (int n = 0; n < 8; ++n) acc[m][n] = (f32x4){0.f, 0.f, 0.f, 0.f};

    auto loadB = [&](int kc, bf16x8* bf_) {
        #pragma unroll
        for (int i = 0; i < 8; ++i)
            bf_[i] = *(const bf16x8*)(Xw + ((size_t)i * KCN + kc) * 512);
    };
    auto loadA = [&](int kc, bf16x8* af) {
        #pragma unroll
        for (int m = 0; m < 8; ++m)
            af[m] = *(const bf16x8*)(Wb + ((size_t)m * KCN + kc) * 512);
    };
    auto compute = [&](const bf16x8* af, const bf16x8* bf_) {
        __builtin_amdgcn_s_setprio(1);
        #pragma unroll
        for (int m = 0; m < 8; ++m)
            #pragma unroll
            for (int n = 0; n < 8; ++n)
                acc[m][n] = __builtin_amdgcn_mfma_f32_16x16x32_bf16(af[m], bf_[n], acc[m][n], 0, 0, 0);
        __builtin_amdgcn_s_setprio(0);
    };

    bf16x8 bA[8], bB[8], aA[8], aB[8];
    loadB(0, bA);
    loadA(0, aA);

    #pragma unroll
    for (int j = 0; j < KCN; ++j) {
        if (j & 1) {
            if (j + 1 < KCN) { loadB(j + 1, bA); loadA(j + 1, aA); }
            compute(aB, bB);
        } else {
            if (j + 1 < KCN) { loadB(j + 1, bB); loadA(j + 1, aB); }
            compute(aA, bA);
        }
    }

    // ---- InstanceNorm stats ----
    #pragma unroll
    for (int m = 0; m < 8; ++m) {
        #pragma unroll
        for (int j = 0; j < 4; ++j) {
            float s = 0.f, q = 0.f;
            #pragma unroll
            for (int n = 0; n < 8; ++n) { float v = acc[m][n][j]; s += v; q += v * v; }
            #pragma unroll
            for (int off = 1; off < 16; off <<= 1) {
                s += __shfl_xor(s, off, 64);
                q += __shfl_xor(q, off, 64);
            }
            if ((l & 15) == 0) {
                int ol = m * 16 + (l >> 4) * 4 + j;
                sP[w][ol] = s;
                qP[w][ol] = q;
            }
        }
    }
    __syncthreads();
    if (t < 128) {
        float s = 0.f, q = 0.f;
        #pragma unroll
        for (int ww = 0; ww < 8; ++ww) { s += sP[ww][t]; q += qP[ww][t]; }
        float mu = s * (1.0f / HW);
        float var = q * (1.0f / HW) - mu * mu;
        int oc = ot * 128 + t;
        st[t][0] = mu;
        st[t][1] = rsqrtf(var + 1e-5f);
        st[t][2] = film[b * 1024 + oc];
        st[t][3] = film[b * 1024 + 512 + oc];
    }
    __syncthreads();

    // ---- apply norm + FiLM + ReLU + residual (bf16 from Xf, L2-hot), store ----
    float* ob = out + ((size_t)b * DD + ot * 128) * HW;
    int q4 = l >> 4;
    #pragma unroll
    for (int m = 0; m < 8; ++m) {
        int kc_m = 4 * ot + (m >> 1);
        int lp = ((m & 1) * 2 + (q4 >> 1)) * 16 + (l & 15);
        int uo = lp * 8 + (q4 & 1) * 4;   // ushort offset within fragment
        #pragma unroll
        for (int n = 0; n < 8; ++n) {
            ushort4 rb = *(const ushort4*)(Xf + ((size_t)b * 64 + w * 8 + n) * (KCN * 512)
                                           + ((size_t)kc_m) * 512 + uo);
            int px = w * 128 + n * 16 + (l & 15);
            #pragma unroll
            for (int jj = 0; jj < 4; ++jj) {
                int ol = m * 16 + q4 * 4 + jj;
                f32x4 sv = *(const f32x4*)&st[ol][0];
                float nrm = (acc[m][n][jj] - sv[0]) * sv[1];
                float rr = sv[2] * nrm + sv[3];
                rr = rr > 0.f ? rr : 0.f;
                float res = bf2f(((const unsigned short*)&rb)[jj]);
                ob[(size_t)ol * HW + px] = res + rr;
            }
        }
    }
}

// ---------------- Fallback (round-1 f32 path) ----------------
__global__ __launch_bounds__(256) void k_conv_in_film(
    const float* __restrict__ fvisu, const float* __restrict__ fcoord,
    const float* __restrict__ cw, const float* __restrict__ film,
    float* __restrict__ out) {
    int L = blockIdx.x;
    int b = L & 63;
    int tgt = L >> 6;
    int o0 = tgt * 16;
    int tid = threadIdx.x;
    __shared__ float xs[8][HW];
    __shared__ float red[16][4][2];
    __shared__ float stats[16][2];
    float acc[16][4];
    #pragma unroll
    for (int o = 0; o < 16; ++o)
        #pragma unroll
        for (int j = 0; j < 4; ++j) acc[o][j] = 0.f;

    const float* xb_v = fvisu + (size_t)b * DD * HW;
    const float* xb_c = fcoord + (size_t)b * 8 * HW;

    for (int c0 = 0; c0 < CIN; c0 += 8) {
        #pragma unroll
        for (int i = 0; i < 8; ++i) {
            int c = c0 + i;
            const float* src = (c < DD) ? (xb_v + (size_t)c * HW) : (xb_c + (size_t)(c - DD) * HW);
            ((float4*)xs[i])[tid] = ((const float4*)src)[tid];
        }
        __syncthreads();
        #pragma unroll
        for (int i = 0; i < 8; ++i) {
            float xv[4];
            #pragma unroll
            for (int j = 0; j < 4; ++j) xv[j] = xs[i][tid + 256 * j];
            #pragma unroll
            for (int o = 0; o < 16; ++o) {
                float wv = cw[(size_t)(o0 + o) * CIN + (c0 + i)];
                #pragma unroll
                for (int j = 0; j < 4; ++j) acc[o][j] = fmaf(wv, xv[j], acc[o][j]);
            }
        }
        __syncthreads();
    }
    int lane = tid & 63, wid = tid >> 6;
    #pragma unroll
    for (int o = 0; o < 16; ++o) {
        float s = 0.f, q = 0.f;
        #pragma unroll
        for (int j = 0; j < 4; ++j) { s += acc[o][j]; q += acc[o][j] * acc[o][j]; }
        #pragma unroll
        for (int off = 32; off; off >>= 1) {
            s += __shfl_down(s, off, 64);
            q += __shfl_down(q, off, 64);
        }
        if (lane == 0) { red[o][wid][0] = s; red[o][wid][1] = q; }
    }
    __syncthreads();
    if (tid < 16) {
        float s = red[tid][0][0] + red[tid][1][0] + red[tid][2][0] + red[tid][3][0];
        float q = red[tid][0][1] + red[tid][1][1] + red[tid][2][1] + red[tid][3][1];
        float mu = s * (1.0f / HW);
        float var = q * (1.0f / HW) - mu * mu;
        stats[tid][0] = mu;
        stats[tid][1] = rsqrtf(var + 1e-5f);
    }
    __syncthreads();
    #pragma unroll
    for (int o = 0; o < 16; ++o) {
        int oc = o0 + o;
        float mu = stats[o][0], rs = stats[o][1];
        float g  = film[b * 1024 + oc];
        float be = film[b * 1024 + 512 + oc];
        const float* fv = xb_v + (size_t)oc * HW;
        float* op = out + ((size_t)b * DD + oc) * HW;
        #pragma unroll
        for (int j = 0; j < 4; ++j) {
            int p = tid + 256 * j;
            float nrm = (acc[o][j] - mu) * rs;
            float rr = g * nrm + be;
            rr = rr > 0.f ? rr : 0.f;
            op[p] = fv[p] + rr;
        }
    }
}

extern "C" void kernel_launch(void* const* d_in, const int* in_sizes, int n_in,
                              void* d_out, int out_size, void* d_ws, size_t ws_size,
                              hipStream_t stream) {
    const float* fvisu  = (const float*)d_in[0];
    const float* fword  = (const float*)d_in[1];
    const float* cscore = (const float*)d_in[2];
    const float* fcoord = (const float*)d_in[3];
    // d_in[4] = gest (unused by reference)
    const int*   wmask  = (const int*)d_in[5];
    const float* amw    = (const float*)d_in[6];
    const float* amb    = (const float*)d_in[7];
    const float* asw    = (const float*)d_in[8];
    const float* asb    = (const float*)d_in[9];
    const float* gw     = (const float*)d_in[10];
    const float* gb     = (const float*)d_in[11];
    const float* cw     = (const float*)d_in[12];
    // d_in[13] = conv1_b: cancels in instance norm, unused

    float* out = (float*)d_out;
    float* ws_tv   = (float*)d_ws;                    // 32768 floats = 128 KB
    float* ws_film = ws_tv + BB * DD;                 // 65536 floats = 256 KB
    unsigned short* Xf  = (unsigned short*)((char*)d_ws + 393216);
    unsigned short* Wf  = (unsigned short*)((char*)d_ws + 393216 + 71303168);
    unsigned short* Whi = (unsigned short*)((char*)d_ws + 393216 + 71303168 + 557056);
    unsigned short* Wlo = Whi + 131072;               // each 256 KB
    float* gwT = (float*)((char*)d_ws + 393216 + 71303168 + 557056 + 524288);  // 2 MB
    const size_t need = 393216 + 71303168 + 557056 + 524288 + 2097152;

    float* out_alang  = out + OUT_ALANG;
    float* out_ascore = out + OUT_ASCORE;

    if (ws_size >= need) {
        k_convert_params<<<328, 256, 0, stream>>>(cw, Wf, amw, Whi, Wlo, gw, gwT);
        k_convert_x<<<BB * KCN, 512, 0, stream>>>(fvisu, fcoord, Xf, ws_tv);
        k_attnscore<<<BB, 256, 0, stream>>>(fword, cscore, ws_tv, Whi, Wlo, amb, asw, asb,
                                            wmask, out_ascore, out_alang);
        k_film<<<BB * 4, 256, 0, stream>>>(out_alang, gwT, gb, ws_film);
        k_gemm_in_film<<<256, 512, 0, stream>>>(Xf, Wf, ws_film, out);
    } else {
        k_tilevisu<<<BB * DD, 256, 0, stream>>>(fvisu, ws_tv);
        k_attnscore_legacy<<<BB * NN, 256, 0, stream>>>(fword, cscore, ws_tv, amw, amb, asw, asb, out_ascore);
        k_lang_film<<<BB * 4, 256, 0, stream>>>(fword, wmask, out_ascore, gw, gb, out_alang, ws_film);
        k_conv_in_film<<<BB * 32, 256, 0, stream>>>(fvisu, fcoord, cw, ws_film, out);
    }
}

// Round 10
// 184.295 us; speedup vs baseline: 3.9958x; 3.9958x over previous
//
#include <hip/hip_runtime.h>
#include <math.h>

#define BB 64
#define DD 512
#define HW 1024
#define NN 20
#define EE 512
#define CIN 520
#define KCN 17            // K chunks of 32 (K padded 520 -> 544)
#define TEMP_F 10.0f

#define OUT_ALANG (BB*DD*HW)            // 33554432
#define OUT_ASCORE (OUT_ALANG + BB*DD)  // 33587200

typedef __bf16 bf16x8 __attribute__((ext_vector_type(8)));
typedef float f32x4 __attribute__((ext_vector_type(4)));

__device__ __forceinline__ unsigned int pack2bf(float a, float b) {
    unsigned int ua = __builtin_bit_cast(unsigned int, a);
    unsigned int ub = __builtin_bit_cast(unsigned int, b);
    ua += 0x7fffu + ((ua >> 16) & 1u);   // RTNE
    ub += 0x7fffu + ((ub >> 16) & 1u);
    return (ua >> 16) | (ub & 0xffff0000u);
}

__device__ __forceinline__ unsigned short bfr(float x) {
    unsigned int u = __builtin_bit_cast(unsigned int, x);
    u += 0x7fffu + ((u >> 16) & 1u);
    return (unsigned short)(u >> 16);
}

__device__ __forceinline__ float bf2f(unsigned short u) {
    unsigned int x = ((unsigned int)u) << 16;
    return __builtin_bit_cast(float, x);
}

// ---------------- Kernel A (fallback only): tile_visu ----------------
__global__ __launch_bounds__(256) void k_tilevisu(const float* __restrict__ fvisu,
                                                  float* __restrict__ tv) {
    int row = blockIdx.x;
    const float4* p = (const float4*)(fvisu + (size_t)row * HW);
    int tid = threadIdx.x;
    float4 v = p[tid];
    float s = v.x + v.y + v.z + v.w;
    #pragma unroll
    for (int off = 32; off; off >>= 1) s += __shfl_down(s, off, 64);
    __shared__ float part[4];
    if ((tid & 63) == 0) part[tid >> 6] = s;
    __syncthreads();
    if (tid == 0) tv[row] = (part[0] + part[1] + part[2] + part[3]) * (1.0f / HW);
}

// ---------------- Kernel X1: fused tile_visu + pack X -> bf16 fragments (float4 loads) ----------------
__global__ __launch_bounds__(512) void k_convert_x(
    const float* __restrict__ fvisu, const float* __restrict__ fcoord,
    unsigned short* __restrict__ Xf, float* __restrict__ tv) {
    int L = blockIdx.x;
    int kc = L % KCN;
    int b  = L / KCN;
    int t = threadIdx.x;
    int co = t >> 7;          // 0..3 (wave-uniform)
    int tl = t & 127;
    int cbase = kc * 32 + co * 8;
    float sums[8];
    #pragma unroll
    for (int j = 0; j < 8; ++j) sums[j] = 0.f;

    #pragma unroll
    for (int i = 0; i < 2; ++i) {
        int p0 = (tl + 128 * i) * 4;
        float4 f4[8];
        #pragma unroll
        for (int j = 0; j < 8; ++j) {
            int c = cbase + j;
            if (c < DD) {
                f4[j] = *(const float4*)&fvisu[((size_t)b * DD + c) * HW + p0];
            } else if (c < CIN) {
                f4[j] = *(const float4*)&fcoord[((size_t)b * 8 + (c - DD)) * HW + p0];
            } else {
                f4[j] = make_float4(0.f, 0.f, 0.f, 0.f);
            }
        }
        #pragma unroll
        for (int j = 0; j < 8; ++j)
            if (cbase + j < DD) sums[j] += f4[j].x + f4[j].y + f4[j].z + f4[j].w;

        size_t base = (((size_t)b * 64 + (p0 >> 4)) * KCN + kc) * 512
                    + (size_t)(co * 16 + (p0 & 15)) * 8;
        #pragma unroll
        for (int i2 = 0; i2 < 4; ++i2) {
            uint4 v;
            v.x = pack2bf(((const float*)&f4[0])[i2], ((const float*)&f4[1])[i2]);
            v.y = pack2bf(((const float*)&f4[2])[i2], ((const float*)&f4[3])[i2]);
            v.z = pack2bf(((const float*)&f4[4])[i2], ((const float*)&f4[5])[i2]);
            v.w = pack2bf(((const float*)&f4[6])[i2], ((const float*)&f4[7])[i2]);
            *(uint4*)&Xf[base + (size_t)i2 * 8] = v;
        }
    }

    #pragma unroll
    for (int j = 0; j < 8; ++j) {
        float s = sums[j];
        #pragma unroll
        for (int off = 32; off; off >>= 1) s += __shfl_down(s, off, 64);
        sums[j] = s;
    }
    __shared__ float red[8][8];
    int w = t >> 6;
    if ((t & 63) == 0) {
        #pragma unroll
        for (int j = 0; j < 8; ++j) red[w][j] = sums[j];
    }
    __syncthreads();
    if (t < 32) {
        int j = t & 7, c2 = t >> 3;
        int c = kc * 32 + c2 * 8 + j;
        if (c < DD) tv[(size_t)b * DD + c] = (red[c2 * 2][j] + red[c2 * 2 + 1][j]) * (1.0f / HW);
    }
}

// ---------------- Kernel X2: merged param converts (Wf | Whi/Wlo | gwT) ----------------
__global__ __launch_bounds__(256) void k_convert_params(
    const float* __restrict__ cw, unsigned short* __restrict__ Wf,
    const float* __restrict__ amw, unsigned short* __restrict__ Whi,
    unsigned short* __restrict__ Wlo,
    const float* __restrict__ gw, float* __restrict__ gwT) {
    int B0 = blockIdx.x;
    int t = threadIdx.x;
    if (B0 < 136) {
        int frag = B0 * 4 + (t >> 6);   // 0..543
        int l = t & 63;
        int M = frag / KCN, kc = frag % KCN;
        int o = M * 16 + (l & 15);
        int k0 = kc * 32 + (l >> 4) * 8;
        float f[8];
        #pragma unroll
        for (int j = 0; j < 8; ++j) {
            int k = k0 + j;
            f[j] = (k < CIN) ? cw[(size_t)o * CIN + k] : 0.f;
        }
        uint4 v;
        v.x = pack2bf(f[0], f[1]);
        v.y = pack2bf(f[2], f[3]);
        v.z = pack2bf(f[4], f[5]);
        v.w = pack2bf(f[6], f[7]);
        *(uint4*)&Wf[(size_t)frag * 512 + (size_t)l * 8] = v;
    } else if (B0 < 200) {
        int fid = (B0 - 136) * 4 + (t >> 6);    // 0..255
        int l = t & 63;
        int o = (fid >> 4) * 16 + (l & 15);
        int k0 = (fid & 15) * 32 + ((l >> 4) & 3) * 8;
        float hi[8], lo[8];
        #pragma unroll
        for (int j = 0; j < 8; ++j) {
            float x = amw[(size_t)o * DD + k0 + j];
            unsigned short h = bfr(x);
            hi[j] = bf2f(h);
            lo[j] = x - hi[j];
        }
        uint4 vh, vl;
        vh.x = pack2bf(hi[0], hi[1]); vh.y = pack2bf(hi[2], hi[3]);
        vh.z = pack2bf(hi[4], hi[5]); vh.w = pack2bf(hi[6], hi[7]);
        vl.x = pack2bf(lo[0], lo[1]); vl.y = pack2bf(lo[2], lo[3]);
        vl.z = pack2bf(lo[4], lo[5]); vl.w = pack2bf(lo[6], lo[7]);
        *(uint4*)&Whi[(size_t)fid * 512 + (size_t)l * 8] = vh;
        *(uint4*)&Wlo[(size_t)fid * 512 + (size_t)l * 8] = vl;
    } else {
        __shared__ float tile[64][65];
        int bt = B0 - 200;
        int rt = bt & 15, kt = bt >> 4;
        int rl = t >> 4;            // 0..15
        int kl = (t & 15) * 4;      // 0..60
        #pragma unroll
        for (int i = 0; i < 4; ++i) {
            int rr = rl + i * 16;
            float4 v = *(const float4*)&gw[(size_t)(rt * 64 + rr) * DD + kt * 64 + kl];
            tile[rr][kl + 0] = v.x; tile[rr][kl + 1] = v.y;
            tile[rr][kl + 2] = v.z; tile[rr][kl + 3] = v.w;
        }
        __syncthreads();
        #pragma unroll
        for (int i = 0; i < 4; ++i) {
            int kk = rl + i * 16;
            float4 v;
            v.x = tile[kl + 0][kk]; v.y = tile[kl + 1][kk];
            v.z = tile[kl + 2][kk]; v.w = tile[kl + 3][kk];
            *(float4*)&gwT[(size_t)(kt * 64 + kk) * 1024 + rt * 64 + kl] = v;
        }
    }
}

// ---------------- Kernel B: attn_score via MFMA hi/lo + fused softmax/mask + attn_lang ----------------
__global__ __launch_bounds__(256) void k_attnscore(
    const float* __restrict__ fword, const float* __restrict__ cs,
    const float* __restrict__ tv, const unsigned short* __restrict__ Whi,
    const unsigned short* __restrict__ Wlo, const float* __restrict__ amb,
    const float* __restrict__ asw, const float* __restrict__ asb,
    const int* __restrict__ wmask, float* __restrict__ out_ascore,
    float* __restrict__ out_alang) {
    int b = blockIdx.x;
    __shared__ unsigned short uhi[2][16][64][8];   // 32 KB: [mt][ks][lane][j]
    __shared__ unsigned short ulo[2][16][64][8];   // 32 KB
    __shared__ float scoreP[4][32];
    __shared__ float asc_sh[NN];
    __shared__ float msh[NN];
    int t = threadIdx.x;

    {
        int n = t & 31, kq = t >> 5;               // kq: k-range of 64
        float csv = (n < NN) ? cs[b * NN + n] : 0.f;
        const float* fwp = fword + ((size_t)b * NN + (n < NN ? n : 0)) * DD;
        const float* tvp = tv + (size_t)b * DD;
        int mt = n >> 4;
        #pragma unroll
        for (int oc = 0; oc < 8; ++oc) {
            int k = kq * 64 + oc * 8;
            float x[8];
            if (n < NN) {
                float4 f0 = *(const float4*)&fwp[k];
                float4 f1 = *(const float4*)&fwp[k + 4];
                float4 t0 = *(const float4*)&tvp[k];
                float4 t1 = *(const float4*)&tvp[k + 4];
                x[0] = f0.x * t0.x * csv; x[1] = f0.y * t0.y * csv;
                x[2] = f0.z * t0.z * csv; x[3] = f0.w * t0.w * csv;
                x[4] = f1.x * t1.x * csv; x[5] = f1.y * t1.y * csv;
                x[6] = f1.z * t1.z * csv; x[7] = f1.w * t1.w * csv;
            } else {
                #pragma unroll
                for (int j = 0; j < 8; ++j) x[j] = 0.f;
            }
            float h[8], lw[8];
            #pragma unroll
            for (int j = 0; j < 8; ++j) {
                h[j] = bf2f(bfr(x[j]));
                lw[j] = x[j] - h[j];
            }
            int ks = k >> 5;
            int l = (n & 15) + ((k >> 3) & 3) * 16;
            uint4 vh, vl;
            vh.x = pack2bf(h[0], h[1]); vh.y = pack2bf(h[2], h[3]);
            vh.z = pack2bf(h[4], h[5]); vh.w = pack2bf(h[6], h[7]);
            vl.x = pack2bf(lw[0], lw[1]); vl.y = pack2bf(lw[2], lw[3]);
            vl.z = pack2bf(lw[4], lw[5]); vl.w = pack2bf(lw[6], lw[7]);
            *(uint4*)&uhi[mt][ks][l][0] = vh;
            *(uint4*)&ulo[mt][ks][l][0] = vl;
        }
    }
    __syncthreads();

    int w = t >> 6, l = t & 63;
    f32x4 acc[2][4];
    #pragma unroll
    for (int mt = 0; mt < 2; ++mt)
        #pragma unroll
        for (int nt = 0; nt < 4; ++nt) acc[mt][nt] = (f32x4){0.f, 0.f, 0.f, 0.f};

    #pragma unroll 4
    for (int ks = 0; ks < 16; ++ks) {
        bf16x8 ah0 = *(const bf16x8*)&uhi[0][ks][l][0];
        bf16x8 ah1 = *(const bf16x8*)&uhi[1][ks][l][0];
        bf16x8 al0 = *(const bf16x8*)&ulo[0][ks][l][0];
        bf16x8 al1 = *(const bf16x8*)&ulo[1][ks][l][0];
        #pragma unroll
        for (int nt = 0; nt < 4; ++nt) {
            size_t fo = ((size_t)((w * 4 + nt) * 16 + ks)) * 512 + (size_t)l * 8;
            bf16x8 bh = *(const bf16x8*)&Whi[fo];
            bf16x8 bl = *(const bf16x8*)&Wlo[fo];
            acc[0][nt] = __builtin_amdgcn_mfma_f32_16x16x32_bf16(ah0, bh, acc[0][nt], 0, 0, 0);
            acc[0][nt] = __builtin_amdgcn_mfma_f32_16x16x32_bf16(al0, bh, acc[0][nt], 0, 0, 0);
            acc[0][nt] = __builtin_amdgcn_mfma_f32_16x16x32_bf16(ah0, bl, acc[0][nt], 0, 0, 0);
            acc[1][nt] = __builtin_amdgcn_mfma_f32_16x16x32_bf16(ah1, bh, acc[1][nt], 0, 0, 0);
            acc[1][nt] = __builtin_amdgcn_mfma_f32_16x16x32_bf16(al1, bh, acc[1][nt], 0, 0, 0);
            acc[1][nt] = __builtin_amdgcn_mfma_f32_16x16x32_bf16(ah1, bl, acc[1][nt], 0, 0, 0);
        }
    }

    float ambv[4], aswv[4];
    #pragma unroll
    for (int nt = 0; nt < 4; ++nt) {
        int o = (w * 4 + nt) * 16 + (l & 15);
        ambv[nt] = amb[o];
        aswv[nt] = asw[o];
    }
    #pragma unroll
    for (int mt = 0; mt < 2; ++mt) {
        #pragma unroll
        for (int j = 0; j < 4; ++j) {
            float p = 0.f;
            #pragma unroll
            for (int nt = 0; nt < 4; ++nt)
                p += aswv[nt] * tanhf(acc[mt][nt][j] + ambv[nt]);
            #pragma unroll
            for (int off = 1; off < 16; off <<= 1) p += __shfl_xor(p, off, 64);
            if ((l & 15) == 0) scoreP[w][mt * 16 + (l >> 4) * 4 + j] = p;
        }
    }
    __syncthreads();
    if (t < NN) {
        float v = scoreP[0][t] + scoreP[1][t] + scoreP[2][t] + scoreP[3][t] + asb[0];
        out_ascore[b * NN + t] = v;
        asc_sh[t] = v;
    }
    __syncthreads();

    if (t == 0) {
        float s[NN];
        float mx = -1e30f;
        for (int n = 0; n < NN; ++n) { s[n] = asc_sh[n] * TEMP_F; mx = fmaxf(mx, s[n]); }
        float se = 0.f;
        for (int n = 0; n < NN; ++n) { s[n] = expf(s[n] - mx); se += s[n]; }
        int m[NN]; int idx = 0;
        for (int n = 0; n < NN; ++n) m[n] = wmask[b * NN + n];
        m[0] = 0;
        for (int n = 0; n < NN; ++n) idx += m[n];
        m[idx] = 0;
        float tot = 0.f;
        for (int n = 0; n < NN; ++n) { float v = (s[n] / se) * (float)m[n]; msh[n] = v; tot += v; }
        float inv = 1.f / (tot + 1e-8f);
        for (int n = 0; n < NN; ++n) msh[n] *= inv;
    }
    __syncthreads();

    #pragma unroll 2
    for (int d = t; d < DD; d += 256) {
        float a = 0.f;
        #pragma unroll
        for (int n = 0; n < NN; ++n) a += msh[n] * fword[((size_t)b * NN + n) * DD + d];
        out_alang[b * DD + d] = a;
    }
}

// ---------------- Kernel B-legacy (fallback only) ----------------
__global__ __launch_bounds__(256) void k_attnscore_legacy(
    const float* __restrict__ fword, const float* __restrict__ cs,
    const float* __restrict__ tv, const float* __restrict__ amw,
    const float* __restrict__ amb, const float* __restrict__ asw,
    const float* __restrict__ asb, float* __restrict__ out_ascore) {
    int bn = blockIdx.x;
    int b = bn / NN, n = bn % NN;
    __shared__ float u[DD];
    __shared__ float part[4];
    int tid = threadIdx.x;
    float csv = cs[b * NN + n];
    for (int d = tid; d < DD; d += 256)
        u[d] = tv[b * DD + d] * fword[((size_t)b * NN + n) * DD + d] * csv;
    __syncthreads();
    int o = tid;
    const float4* wrow = (const float4*)(amw + (size_t)o * DD);
    const float4* uv = (const float4*)u;
    float dot = 0.f;
    #pragma unroll 4
    for (int i = 0; i < DD / 4; ++i) {
        float4 w4 = wrow[i]; float4 u4 = uv[i];
        dot += w4.x * u4.x + w4.y * u4.y + w4.z * u4.z + w4.w * u4.w;
    }
    float contrib = asw[o] * tanhf(dot + amb[o]);
    #pragma unroll
    for (int off = 32; off; off >>= 1) contrib += __shfl_down(contrib, off, 64);
    if ((tid & 63) == 0) part[tid >> 6] = contrib;
    __syncthreads();
    if (tid == 0) out_ascore[b * NN + n] = part[0] + part[1] + part[2] + part[3] + asb[0];
}

// ---------------- Kernel C (fallback only): mask_softmax + attn_lang + FiLM decode ----------------
__global__ __launch_bounds__(256) void k_lang_film(
    const float* __restrict__ fword, const int* __restrict__ wmask,
    const float* __restrict__ ascore, const float* __restrict__ gw,
    const float* __restrict__ gb, float* __restrict__ out_alang,
    float* __restrict__ ws_film) {
    int b = blockIdx.x >> 2;
    int qd = blockIdx.x & 3;
    __shared__ float ms[NN];
    __shared__ float al[DD];
    int tid = threadIdx.x;
    if (tid == 0) {
        float s[NN];
        float mx = -1e30f;
        for (int n = 0; n < NN; ++n) { s[n] = ascore[b * NN + n] * TEMP_F; mx = fmaxf(mx, s[n]); }
        float se = 0.f;
        for (int n = 0; n < NN; ++n) { s[n] = expf(s[n] - mx); se += s[n]; }
        int m[NN]; int idx = 0;
        for (int n = 0; n < NN; ++n) m[n] = wmask[b * NN + n];
        m[0] = 0;
        for (int n = 0; n < NN; ++n) idx += m[n];
        m[idx] = 0;
        float tot = 0.f;
        for (int n = 0; n < NN; ++n) { float v = (s[n] / se) * (float)m[n]; ms[n] = v; tot += v; }
        float inv = 1.f / (tot + 1e-8f);
        for (int n = 0; n < NN; ++n) ms[n] *= inv;
    }
    __syncthreads();
    for (int d = tid; d < DD; d += 256) {
        float a = 0.f;
        #pragma unroll
        for (int n = 0; n < NN; ++n) a += ms[n] * fword[((size_t)b * NN + n) * DD + d];
        al[d] = a;
        if (qd == 0) out_alang[b * DD + d] = a;
    }
    __syncthreads();
    {
        int r = qd * 256 + tid;
        const float4* grow = (const float4*)(gw + (size_t)r * DD);
        const float4* av = (const float4*)al;
        float dot = 0.f;
        #pragma unroll 4
        for (int i = 0; i < DD / 4; ++i) {
            float4 g4 = grow[i]; float4 a4 = av[i];
            dot += g4.x * a4.x + g4.y * a4.y + g4.z * a4.z + g4.w * a4.w;
        }
        ws_film[b * 2 * EE + r] = tanhf(dot + gb[r]);
    }
}

// ---------------- Kernel C2: film GEMV, coalesced columns, grid BB*4 ----------------
__global__ __launch_bounds__(256) void k_film(
    const float* __restrict__ alang, const float* __restrict__ gwT,
    const float* __restrict__ gb, float* __restrict__ ws_film) {
    int b = blockIdx.x >> 2;
    int q = blockIdx.x & 3;
    __shared__ float al[DD];
    int t = threadIdx.x;
    al[t] = alang[b * DD + t];
    al[t + 256] = alang[b * DD + t + 256];
    __syncthreads();
    int r = q * 256 + t;
    float acc = 0.f;
    #pragma unroll 8
    for (int k = 0; k < DD; ++k)
        acc += al[k] * gwT[(size_t)k * 1024 + r];
    ws_film[b * 1024 + r] = tanhf(acc + gb[r]);
}

// ---------------- Kernel D: all-register MFMA GEMM (M=64, R8 geometry) + IN + FiLM + residual ----------------
// grid 512: block (b, ot) = 64 o-chans x 1024 px, 8 waves, wave tile 64x128.
// acc[4][8] = 128 VGPR + dbuf 96 -> no spill at 2 waves/SIMD (verified R7/R8: VGPR_Count=128).
__global__ __launch_bounds__(512, 2) void k_gemm_in_film(
    const unsigned short* __restrict__ Xf, const unsigned short* __restrict__ Wf,
    const float* __restrict__ film, float* __restrict__ out) {
    __shared__ float sP[8][64];
    __shared__ float qP[8][64];
    __shared__ float st[64][4];    // mu, rs, gamma, beta
    int L = blockIdx.x;
    int ot = (L >> 3) & 7;                 // same-b blocks: L = c + 8*ot + 64*h
    int b  = (L >> 6) * 8 + (L & 7);       // -> same XCD (L%8 fixed), same round
    int t = threadIdx.x;
    int w = t >> 6, l = t & 63;

    const unsigned short* Xw = Xf + ((size_t)b * 64 + w * 8) * (KCN * 512) + (size_t)l * 8;
    const unsigned short* Wb = Wf + (size_t)(ot * 4) * (KCN * 512) + (size_t)l * 8;
    int ot2 = 2 * ot;

    f32x4 acc[4][8];
    #pragma unroll
    for (int m = 0; m < 4; ++m)
        #pragma unroll
        for (int n = 0; n < 8; ++n) acc[m][n] = (f32x4){0.f, 0.f, 0.f, 0.f};

    auto kcof = [&](int j) -> int {
        if (j < 15) return j + (j >= ot2 ? 2 : 0);
        return (j == 15) ? ot2 : (ot2 + 1);
    };
    auto loadB = [&](int j, bf16x8* bf_) {
        int kc = kcof(j);
        #pragma unroll
        for (int i = 0; i < 8; ++i)
            bf_[i] = *(const bf16x8*)(Xw + ((size_t)i * KCN + kc) * 512);
    };
    auto loadA = [&](int j, bf16x8* af) {
        int kc = kcof(j);
        #pragma unroll
        for (int m = 0; m < 4; ++m)
            af[m] = *(const bf16x8*)(Wb + ((size_t)m * KCN + kc) * 512);
    };
    auto compute = [&](const bf16x8* af, const bf16x8* bf_) {
        __builtin_amdgcn_s_setprio(1);
        #pragma unroll
        for (int m = 0; m < 4; ++m)
            #pragma unroll
            for (int n = 0; n < 8; ++n)
                acc[m][n] = __builtin_amdgcn_mfma_f32_16x16x32_bf16(af[m], bf_[n], acc[m][n], 0, 0, 0);
        __builtin_amdgcn_s_setprio(0);
    };

    bf16x8 bA[8], bB[8], aA[4], aB[4];
    loadB(0, bA);
    loadA(0, aA);

    #pragma unroll
    for (int j = 0; j < KCN; ++j) {
        if (j & 1) {
            if (j + 1 < KCN) { loadB(j + 1, bA); loadA(j + 1, aA); }
            compute(aB, bB);
        } else {
            if (j + 1 < KCN) { loadB(j + 1, bB); loadA(j + 1, aB); }
            compute(aA, bA);
        }
    }

    // ---- InstanceNorm stats ----
    #pragma unroll
    for (int m = 0; m < 4; ++m) {
        #pragma unroll
        for (int j = 0; j < 4; ++j) {
            float s = 0.f, q = 0.f;
            #pragma unroll
            for (int n = 0; n < 8; ++n) { float v = acc[m][n][j]; s += v; q += v * v; }
            #pragma unroll
            for (int off = 1; off < 16; off <<= 1) {
                s += __shfl_xor(s, off, 64);
                q += __shfl_xor(q, off, 64);
            }
            if ((l & 15) == 0) {
                int ol = m * 16 + (l >> 4) * 4 + j;
                sP[w][ol] = s;
                qP[w][ol] = q;
            }
        }
    }
    __syncthreads();
    if (t < 64) {
        float s = 0.f, q = 0.f;
        #pragma unroll
        for (int ww = 0; ww < 8; ++ww) { s += sP[ww][t]; q += qP[ww][t]; }
        float mu = s * (1.0f / HW);
        float var = q * (1.0f / HW) - mu * mu;
        int oc = ot * 64 + t;
        st[t][0] = mu;
        st[t][1] = rsqrtf(var + 1e-5f);
        st[t][2] = film[b * 1024 + oc];
        st[t][3] = film[b * 1024 + 512 + oc];
    }
    __syncthreads();

    // ---- apply norm + FiLM + ReLU + residual (bf16 from Xf, L2-hot), store ----
    float* ob = out + ((size_t)b * DD + ot * 64) * HW;
    int q4 = l >> 4;
    #pragma unroll
    for (int m = 0; m < 4; ++m) {
        int kc_m = ot2 + (m >> 1);
        int lp = ((m & 1) * 2 + (q4 >> 1)) * 16 + (l & 15);
        int uo = lp * 8 + (q4 & 1) * 4;   // ushort offset within fragment
        #pragma unroll
        for (int n = 0; n < 8; ++n) {
            ushort4 rb = *(const ushort4*)(Xf + ((size_t)b * 64 + w * 8 + n) * (KCN * 512)
                                           + ((size_t)kc_m) * 512 + uo);
            int px = w * 128 + n * 16 + (l & 15);
            #pragma unroll
            for (int jj = 0; jj < 4; ++jj) {
                int ol = m * 16 + q4 * 4 + jj;
                f32x4 sv = *(const f32x4*)&st[ol][0];
                float nrm = (acc[m][n][jj] - sv[0]) * sv[1];
                float rr = sv[2] * nrm + sv[3];
                rr = rr > 0.f ? rr : 0.f;
                float res = bf2f(((const unsigned short*)&rb)[jj]);
                ob[(size_t)ol * HW + px] = res + rr;
            }
        }
    }
}

// ---------------- Fallback (round-1 f32 path) ----------------
__global__ __launch_bounds__(256) void k_conv_in_film(
    const float* __restrict__ fvisu, const float* __restrict__ fcoord,
    const float* __restrict__ cw, const float* __restrict__ film,
    float* __restrict__ out) {
    int L = blockIdx.x;
    int b = L & 63;
    int tgt = L >> 6;
    int o0 = tgt * 16;
    int tid = threadIdx.x;
    __shared__ float xs[8][HW];
    __shared__ float red[16][4][2];
    __shared__ float stats[16][2];
    float acc[16][4];
    #pragma unroll
    for (int o = 0; o < 16; ++o)
        #pragma unroll
        for (int j = 0; j < 4; ++j) acc[o][j] = 0.f;

    const float* xb_v = fvisu + (size_t)b * DD * HW;
    const float* xb_c = fcoord + (size_t)b * 8 * HW;

    for (int c0 = 0; c0 < CIN; c0 += 8) {
        #pragma unroll
        for (int i = 0; i < 8; ++i) {
            int c = c0 + i;
            const float* src = (c < DD) ? (xb_v + (size_t)c * HW) : (xb_c + (size_t)(c - DD) * HW);
            ((float4*)xs[i])[tid] = ((const float4*)src)[tid];
        }
        __syncthreads();
        #pragma unroll
        for (int i = 0; i < 8; ++i) {
            float xv[4];
            #pragma unroll
            for (int j = 0; j < 4; ++j) xv[j] = xs[i][tid + 256 * j];
            #pragma unroll
            for (int o = 0; o < 16; ++o) {
                float wv = cw[(size_t)(o0 + o) * CIN + (c0 + i)];
                #pragma unroll
                for (int j = 0; j < 4; ++j) acc[o][j] = fmaf(wv, xv[j], acc[o][j]);
            }
        }
        __syncthreads();
    }
    int lane = tid & 63, wid = tid >> 6;
    #pragma unroll
    for (int o = 0; o < 16; ++o) {
        float s = 0.f, q = 0.f;
        #pragma unroll
        for (int j = 0; j < 4; ++j) { s += acc[o][j]; q += acc[o][j] * acc[o][j]; }
        #pragma unroll
        for (int off = 32; off; off >>= 1) {
            s += __shfl_down(s, off, 64);
            q += __shfl_down(q, off, 64);
        }
        if (lane == 0) { red[o][wid][0] = s; red[o][wid][1] = q; }
    }
    __syncthreads();
    if (tid < 16) {
        float s = red[tid][0][0] + red[tid][1][0] + red[tid][2][0] + red[tid][3][0];
        float q = red[tid][0][1] + red[tid][1][1] + red[tid][2][1] + red[tid][3][1];
        float mu = s * (1.0f / HW);
        float var = q * (1.0f / HW) - mu * mu;
        stats[tid][0] = mu;
        stats[tid][1] = rsqrtf(var + 1e-5f);
    }
    __syncthreads();
    #pragma unroll
    for (int o = 0; o < 16; ++o) {
        int oc = o0 + o;
        float mu = stats[o][0], rs = stats[o][1];
        float g  = film[b * 1024 + oc];
        float be = film[b * 1024 + 512 + oc];
        const float* fv = xb_v + (size_t)oc * HW;
        float* op = out + ((size_t)b * DD + oc) * HW;
        #pragma unroll
        for (int j = 0; j < 4; ++j) {
            int p = tid + 256 * j;
            float nrm = (acc[o][j] - mu) * rs;
            float rr = g * nrm + be;
            rr = rr > 0.f ? rr : 0.f;
            op[p] = fv[p] + rr;
        }
    }
}

extern "C" void kernel_launch(void* const* d_in, const int* in_sizes, int n_in,
                              void* d_out, int out_size, void* d_ws, size_t ws_size,
                              hipStream_t stream) {
    const float* fvisu  = (const float*)d_in[0];
    const float* fword  = (const float*)d_in[1];
    const float* cscore = (const float*)d_in[2];
    const float* fcoord = (const float*)d_in[3];
    // d_in[4] = gest (unused by reference)
    const int*   wmask  = (const int*)d_in[5];
    const float* amw    = (const float*)d_in[6];
    const float* amb    = (const float*)d_in[7];
    const float* asw    = (const float*)d_in[8];
    const float* asb    = (const float*)d_in[9];
    const float* gw     = (const float*)d_in[10];
    const float* gb     = (const float*)d_in[11];
    const float* cw     = (const float*)d_in[12];
    // d_in[13] = conv1_b: cancels in instance norm, unused

    float* out = (float*)d_out;
    float* ws_tv   = (float*)d_ws;                    // 32768 floats = 128 KB
    float* ws_film = ws_tv + BB * DD;                 // 65536 floats = 256 KB
    unsigned short* Xf  = (unsigned short*)((char*)d_ws + 393216);
    unsigned short* Wf  = (unsigned short*)((char*)d_ws + 393216 + 71303168);
    unsigned short* Whi = (unsigned short*)((char*)d_ws + 393216 + 71303168 + 557056);
    unsigned short* Wlo = Whi + 131072;               // each 256 KB
    float* gwT = (float*)((char*)d_ws + 393216 + 71303168 + 557056 + 524288);  // 2 MB
    const size_t need = 393216 + 71303168 + 557056 + 524288 + 2097152;

    float* out_alang  = out + OUT_ALANG;
    float* out_ascore = out + OUT_ASCORE;

    if (ws_size >= need) {
        k_convert_params<<<328, 256, 0, stream>>>(cw, Wf, amw, Whi, Wlo, gw, gwT);
        k_convert_x<<<BB * KCN, 512, 0, stream>>>(fvisu, fcoord, Xf, ws_tv);
        k_attnscore<<<BB, 256, 0, stream>>>(fword, cscore, ws_tv, Whi, Wlo, amb, asw, asb,
                                            wmask, out_ascore, out_alang);
        k_film<<<BB * 4, 256, 0, stream>>>(out_alang, gwT, gb, ws_film);
        k_gemm_in_film<<<512, 512, 0, stream>>>(Xf, Wf, ws_film, out);
    } else {
        k_tilevisu<<<BB * DD, 256, 0, stream>>>(fvisu, ws_tv);
        k_attnscore_legacy<<<BB * NN, 256, 0, stream>>>(fword, cscore, ws_tv, amw, amb, asw, asb, out_ascore);
        k_lang_film<<<BB * 4, 256, 0, stream>>>(fword, wmask, out_ascore, gw, gb, out_alang, ws_film);
        k_conv_in_film<<<BB * 32, 256, 0, stream>>>(fvisu, fcoord, cw, ws_film, out);
    }
}

// Round 11
// 175.564 us; speedup vs baseline: 4.1945x; 1.0497x over previous
//
#include <hip/hip_runtime.h>
#include <math.h>

#define BB 64
#define DD 512
#define HW 1024
#define NN 20
#define EE 512
#define CIN 520
#define KCN 17            // K chunks of 32 (K padded 520 -> 544)
#define TEMP_F 10.0f

#define OUT_ALANG (BB*DD*HW)            // 33554432
#define OUT_ASCORE (OUT_ALANG + BB*DD)  // 33587200

typedef __bf16 bf16x8 __attribute__((ext_vector_type(8)));
typedef float f32x4 __attribute__((ext_vector_type(4)));

__device__ __forceinline__ unsigned int pack2bf(float a, float b) {
    unsigned int ua = __builtin_bit_cast(unsigned int, a);
    unsigned int ub = __builtin_bit_cast(unsigned int, b);
    ua += 0x7fffu + ((ua >> 16) & 1u);   // RTNE
    ub += 0x7fffu + ((ub >> 16) & 1u);
    return (ua >> 16) | (ub & 0xffff0000u);
}

__device__ __forceinline__ unsigned short bfr(float x) {
    unsigned int u = __builtin_bit_cast(unsigned int, x);
    u += 0x7fffu + ((u >> 16) & 1u);
    return (unsigned short)(u >> 16);
}

__device__ __forceinline__ float bf2f(unsigned short u) {
    unsigned int x = ((unsigned int)u) << 16;
    return __builtin_bit_cast(float, x);
}

// ---------------- Kernel A (fallback only): tile_visu ----------------
__global__ __launch_bounds__(256) void k_tilevisu(const float* __restrict__ fvisu,
                                                  float* __restrict__ tv) {
    int row = blockIdx.x;
    const float4* p = (const float4*)(fvisu + (size_t)row * HW);
    int tid = threadIdx.x;
    float4 v = p[tid];
    float s = v.x + v.y + v.z + v.w;
    #pragma unroll
    for (int off = 32; off; off >>= 1) s += __shfl_down(s, off, 64);
    __shared__ float part[4];
    if ((tid & 63) == 0) part[tid >> 6] = s;
    __syncthreads();
    if (tid == 0) tv[row] = (part[0] + part[1] + part[2] + part[3]) * (1.0f / HW);
}

// ---------------- Kernel X1: fused tile_visu + pack X -> bf16 fragments ----------------
// v3: LDS-staged stores. Phase 1: float4 loads + pack -> LDS frag[64][528] (padded).
// Phase 2: each wave streams 8 fragments as contiguous 1KB stores (full lines, no RMW).
__global__ __launch_bounds__(512, 2) void k_convert_x(
    const float* __restrict__ fvisu, const float* __restrict__ fcoord,
    unsigned short* __restrict__ Xf, float* __restrict__ tv) {
    __shared__ unsigned short frag[64][528];   // 67.6 KB (8-ushort row pad vs 512)
    __shared__ float red[8][8];
    int L = blockIdx.x;
    int kc = L % KCN;
    int b  = L / KCN;
    int t = threadIdx.x;
    int co = t >> 7;          // 0..3 (wave-uniform k-octet)
    int tl = t & 127;
    int cbase = kc * 32 + co * 8;
    float sums[8];
    #pragma unroll
    for (int j = 0; j < 8; ++j) sums[j] = 0.f;

    #pragma unroll
    for (int i = 0; i < 2; ++i) {
        int p0 = (tl + 128 * i) * 4;
        float4 f4[8];
        #pragma unroll
        for (int j = 0; j < 8; ++j) {
            int c = cbase + j;
            if (c < DD) {
                f4[j] = *(const float4*)&fvisu[((size_t)b * DD + c) * HW + p0];
            } else if (c < CIN) {
                f4[j] = *(const float4*)&fcoord[((size_t)b * 8 + (c - DD)) * HW + p0];
            } else {
                f4[j] = make_float4(0.f, 0.f, 0.f, 0.f);
            }
        }
        #pragma unroll
        for (int j = 0; j < 8; ++j)
            if (cbase + j < DD) sums[j] += f4[j].x + f4[j].y + f4[j].z + f4[j].w;

        int P = p0 >> 4;
        #pragma unroll
        for (int i2 = 0; i2 < 4; ++i2) {
            uint4 v;
            v.x = pack2bf(((const float*)&f4[0])[i2], ((const float*)&f4[1])[i2]);
            v.y = pack2bf(((const float*)&f4[2])[i2], ((const float*)&f4[3])[i2]);
            v.z = pack2bf(((const float*)&f4[4])[i2], ((const float*)&f4[5])[i2]);
            v.w = pack2bf(((const float*)&f4[6])[i2], ((const float*)&f4[7])[i2]);
            int unit = co * 16 + (p0 & 15) + i2;   // fragment 16B-unit index
            *(uint4*)&frag[P][unit * 8] = v;
        }
    }

    // tv channel-mean partials
    #pragma unroll
    for (int j = 0; j < 8; ++j) {
        float s = sums[j];
        #pragma unroll
        for (int off = 32; off; off >>= 1) s += __shfl_down(s, off, 64);
        sums[j] = s;
    }
    int w = t >> 6, l = t & 63;
    if (l == 0) {
        #pragma unroll
        for (int j = 0; j < 8; ++j) red[w][j] = sums[j];
    }
    __syncthreads();

    // Phase 2: coalesced fragment stores — 1KB contiguous per wave-instruction
    #pragma unroll
    for (int fi = 0; fi < 8; ++fi) {
        int f = w * 8 + fi;
        uint4 v = *(const uint4*)&frag[f][l * 8];
        *(uint4*)&Xf[(((size_t)b * 64 + f) * KCN + kc) * 512 + (size_t)l * 8] = v;
    }

    if (t < 32) {
        int j = t & 7, c2 = t >> 3;
        int c = kc * 32 + c2 * 8 + j;
        if (c < DD) tv[(size_t)b * DD + c] = (red[c2 * 2][j] + red[c2 * 2 + 1][j]) * (1.0f / HW);
    }
}

// ---------------- Kernel X2: merged param converts (Wf | Whi/Wlo | gwT) ----------------
__global__ __launch_bounds__(256) void k_convert_params(
    const float* __restrict__ cw, unsigned short* __restrict__ Wf,
    const float* __restrict__ amw, unsigned short* __restrict__ Whi,
    unsigned short* __restrict__ Wlo,
    const float* __restrict__ gw, float* __restrict__ gwT) {
    int B0 = blockIdx.x;
    int t = threadIdx.x;
    if (B0 < 136) {
        int frag = B0 * 4 + (t >> 6);   // 0..543
        int l = t & 63;
        int M = frag / KCN, kc = frag % KCN;
        int o = M * 16 + (l & 15);
        int k0 = kc * 32 + (l >> 4) * 8;
        float f[8];
        #pragma unroll
        for (int j = 0; j < 8; ++j) {
            int k = k0 + j;
            f[j] = (k < CIN) ? cw[(size_t)o * CIN + k] : 0.f;
        }
        uint4 v;
        v.x = pack2bf(f[0], f[1]);
        v.y = pack2bf(f[2], f[3]);
        v.z = pack2bf(f[4], f[5]);
        v.w = pack2bf(f[6], f[7]);
        *(uint4*)&Wf[(size_t)frag * 512 + (size_t)l * 8] = v;
    } else if (B0 < 200) {
        int fid = (B0 - 136) * 4 + (t >> 6);    // 0..255
        int l = t & 63;
        int o = (fid >> 4) * 16 + (l & 15);
        int k0 = (fid & 15) * 32 + ((l >> 4) & 3) * 8;
        float hi[8], lo[8];
        #pragma unroll
        for (int j = 0; j < 8; ++j) {
            float x = amw[(size_t)o * DD + k0 + j];
            unsigned short h = bfr(x);
            hi[j] = bf2f(h);
            lo[j] = x - hi[j];
        }
        uint4 vh, vl;
        vh.x = pack2bf(hi[0], hi[1]); vh.y = pack2bf(hi[2], hi[3]);
        vh.z = pack2bf(hi[4], hi[5]); vh.w = pack2bf(hi[6], hi[7]);
        vl.x = pack2bf(lo[0], lo[1]); vl.y = pack2bf(lo[2], lo[3]);
        vl.z = pack2bf(lo[4], lo[5]); vl.w = pack2bf(lo[6], lo[7]);
        *(uint4*)&Whi[(size_t)fid * 512 + (size_t)l * 8] = vh;
        *(uint4*)&Wlo[(size_t)fid * 512 + (size_t)l * 8] = vl;
    } else {
        __shared__ float tile[64][65];
        int bt = B0 - 200;
        int rt = bt & 15, kt = bt >> 4;
        int rl = t >> 4;            // 0..15
        int kl = (t & 15) * 4;      // 0..60
        #pragma unroll
        for (int i = 0; i < 4; ++i) {
            int rr = rl + i * 16;
            float4 v = *(const float4*)&gw[(size_t)(rt * 64 + rr) * DD + kt * 64 + kl];
            tile[rr][kl + 0] = v.x; tile[rr][kl + 1] = v.y;
            tile[rr][kl + 2] = v.z; tile[rr][kl + 3] = v.w;
        }
        __syncthreads();
        #pragma unroll
        for (int i = 0; i < 4; ++i) {
            int kk = rl + i * 16;
            float4 v;
            v.x = tile[kl + 0][kk]; v.y = tile[kl + 1][kk];
            v.z = tile[kl + 2][kk]; v.w = tile[kl + 3][kk];
            *(float4*)&gwT[(size_t)(kt * 64 + kk) * 1024 + rt * 64 + kl] = v;
        }
    }
}

// ---------------- Kernel B: attn_score via MFMA hi/lo + fused softmax/mask + attn_lang ----------------
__global__ __launch_bounds__(256) void k_attnscore(
    const float* __restrict__ fword, const float* __restrict__ cs,
    const float* __restrict__ tv, const unsigned short* __restrict__ Whi,
    const unsigned short* __restrict__ Wlo, const float* __restrict__ amb,
    const float* __restrict__ asw, const float* __restrict__ asb,
    const int* __restrict__ wmask, float* __restrict__ out_ascore,
    float* __restrict__ out_alang) {
    int b = blockIdx.x;
    __shared__ unsigned short uhi[2][16][64][8];   // 32 KB: [mt][ks][lane][j]
    __shared__ unsigned short ulo[2][16][64][8];   // 32 KB
    __shared__ float scoreP[4][32];
    __shared__ float asc_sh[NN];
    __shared__ float msh[NN];
    int t = threadIdx.x;

    {
        int n = t & 31, kq = t >> 5;               // kq: k-range of 64
        float csv = (n < NN) ? cs[b * NN + n] : 0.f;
        const float* fwp = fword + ((size_t)b * NN + (n < NN ? n : 0)) * DD;
        const float* tvp = tv + (size_t)b * DD;
        int mt = n >> 4;
        #pragma unroll
        for (int oc = 0; oc < 8; ++oc) {
            int k = kq * 64 + oc * 8;
            float x[8];
            if (n < NN) {
                float4 f0 = *(const float4*)&fwp[k];
                float4 f1 = *(const float4*)&fwp[k + 4];
                float4 t0 = *(const float4*)&tvp[k];
                float4 t1 = *(const float4*)&tvp[k + 4];
                x[0] = f0.x * t0.x * csv; x[1] = f0.y * t0.y * csv;
                x[2] = f0.z * t0.z * csv; x[3] = f0.w * t0.w * csv;
                x[4] = f1.x * t1.x * csv; x[5] = f1.y * t1.y * csv;
                x[6] = f1.z * t1.z * csv; x[7] = f1.w * t1.w * csv;
            } else {
                #pragma unroll
                for (int j = 0; j < 8; ++j) x[j] = 0.f;
            }
            float h[8], lw[8];
            #pragma unroll
            for (int j = 0; j < 8; ++j) {
                h[j] = bf2f(bfr(x[j]));
                lw[j] = x[j] - h[j];
            }
            int ks = k >> 5;
            int l = (n & 15) + ((k >> 3) & 3) * 16;
            uint4 vh, vl;
            vh.x = pack2bf(h[0], h[1]); vh.y = pack2bf(h[2], h[3]);
            vh.z = pack2bf(h[4], h[5]); vh.w = pack2bf(h[6], h[7]);
            vl.x = pack2bf(lw[0], lw[1]); vl.y = pack2bf(lw[2], lw[3]);
            vl.z = pack2bf(lw[4], lw[5]); vl.w = pack2bf(lw[6], lw[7]);
            *(uint4*)&uhi[mt][ks][l][0] = vh;
            *(uint4*)&ulo[mt][ks][l][0] = vl;
        }
    }
    __syncthreads();

    int w = t >> 6, l = t & 63;
    f32x4 acc[2][4];
    #pragma unroll
    for (int mt = 0; mt < 2; ++mt)
        #pragma unroll
        for (int nt = 0; nt < 4; ++nt) acc[mt][nt] = (f32x4){0.f, 0.f, 0.f, 0.f};

    #pragma unroll 4
    for (int ks = 0; ks < 16; ++ks) {
        bf16x8 ah0 = *(const bf16x8*)&uhi[0][ks][l][0];
        bf16x8 ah1 = *(const bf16x8*)&uhi[1][ks][l][0];
        bf16x8 al0 = *(const bf16x8*)&ulo[0][ks][l][0];
        bf16x8 al1 = *(const bf16x8*)&ulo[1][ks][l][0];
        #pragma unroll
        for (int nt = 0; nt < 4; ++nt) {
            size_t fo = ((size_t)((w * 4 + nt) * 16 + ks)) * 512 + (size_t)l * 8;
            bf16x8 bh = *(const bf16x8*)&Whi[fo];
            bf16x8 bl = *(const bf16x8*)&Wlo[fo];
            acc[0][nt] = __builtin_amdgcn_mfma_f32_16x16x32_bf16(ah0, bh, acc[0][nt], 0, 0, 0);
            acc[0][nt] = __builtin_amdgcn_mfma_f32_16x16x32_bf16(al0, bh, acc[0][nt], 0, 0, 0);
            acc[0][nt] = __builtin_amdgcn_mfma_f32_16x16x32_bf16(ah0, bl, acc[0][nt], 0, 0, 0);
            acc[1][nt] = __builtin_amdgcn_mfma_f32_16x16x32_bf16(ah1, bh, acc[1][nt], 0, 0, 0);
            acc[1][nt] = __builtin_amdgcn_mfma_f32_16x16x32_bf16(al1, bh, acc[1][nt], 0, 0, 0);
            acc[1][nt] = __builtin_amdgcn_mfma_f32_16x16x32_bf16(ah1, bl, acc[1][nt], 0, 0, 0);
        }
    }

    float ambv[4], aswv[4];
    #pragma unroll
    for (int nt = 0; nt < 4; ++nt) {
        int o = (w * 4 + nt) * 16 + (l & 15);
        ambv[nt] = amb[o];
        aswv[nt] = asw[o];
    }
    #pragma unroll
    for (int mt = 0; mt < 2; ++mt) {
        #pragma unroll
        for (int j = 0; j < 4; ++j) {
            float p = 0.f;
            #pragma unroll
            for (int nt = 0; nt < 4; ++nt)
                p += aswv[nt] * tanhf(acc[mt][nt][j] + ambv[nt]);
            #pragma unroll
            for (int off = 1; off < 16; off <<= 1) p += __shfl_xor(p, off, 64);
            if ((l & 15) == 0) scoreP[w][mt * 16 + (l >> 4) * 4 + j] = p;
        }
    }
    __syncthreads();
    if (t < NN) {
        float v = scoreP[0][t] + scoreP[1][t] + scoreP[2][t] + scoreP[3][t] + asb[0];
        out_ascore[b * NN + t] = v;
        asc_sh[t] = v;
    }
    __syncthreads();

    if (t == 0) {
        float s[NN];
        float mx = -1e30f;
        for (int n = 0; n < NN; ++n) { s[n] = asc_sh[n] * TEMP_F; mx = fmaxf(mx, s[n]); }
        float se = 0.f;
        for (int n = 0; n < NN; ++n) { s[n] = expf(s[n] - mx); se += s[n]; }
        int m[NN]; int idx = 0;
        for (int n = 0; n < NN; ++n) m[n] = wmask[b * NN + n];
        m[0] = 0;
        for (int n = 0; n < NN; ++n) idx += m[n];
        m[idx] = 0;
        float tot = 0.f;
        for (int n = 0; n < NN; ++n) { float v = (s[n] / se) * (float)m[n]; msh[n] = v; tot += v; }
        float inv = 1.f / (tot + 1e-8f);
        for (int n = 0; n < NN; ++n) msh[n] *= inv;
    }
    __syncthreads();

    #pragma unroll 2
    for (int d = t; d < DD; d += 256) {
        float a = 0.f;
        #pragma unroll
        for (int n = 0; n < NN; ++n) a += msh[n] * fword[((size_t)b * NN + n) * DD + d];
        out_alang[b * DD + d] = a;
    }
}

// ---------------- Kernel B-legacy (fallback only) ----------------
__global__ __launch_bounds__(256) void k_attnscore_legacy(
    const float* __restrict__ fword, const float* __restrict__ cs,
    const float* __restrict__ tv, const float* __restrict__ amw,
    const float* __restrict__ amb, const float* __restrict__ asw,
    const float* __restrict__ asb, float* __restrict__ out_ascore) {
    int bn = blockIdx.x;
    int b = bn / NN, n = bn % NN;
    __shared__ float u[DD];
    __shared__ float part[4];
    int tid = threadIdx.x;
    float csv = cs[b * NN + n];
    for (int d = tid; d < DD; d += 256)
        u[d] = tv[b * DD + d] * fword[((size_t)b * NN + n) * DD + d] * csv;
    __syncthreads();
    int o = tid;
    const float4* wrow = (const float4*)(amw + (size_t)o * DD);
    const float4* uv = (const float4*)u;
    float dot = 0.f;
    #pragma unroll 4
    for (int i = 0; i < DD / 4; ++i) {
        float4 w4 = wrow[i]; float4 u4 = uv[i];
        dot += w4.x * u4.x + w4.y * u4.y + w4.z * u4.z + w4.w * u4.w;
    }
    float contrib = asw[o] * tanhf(dot + amb[o]);
    #pragma unroll
    for (int off = 32; off; off >>= 1) contrib += __shfl_down(contrib, off, 64);
    if ((tid & 63) == 0) part[tid >> 6] = contrib;
    __syncthreads();
    if (tid == 0) out_ascore[b * NN + n] = part[0] + part[1] + part[2] + part[3] + asb[0];
}

// ---------------- Kernel C (fallback only): mask_softmax + attn_lang + FiLM decode ----------------
__global__ __launch_bounds__(256) void k_lang_film(
    const float* __restrict__ fword, const int* __restrict__ wmask,
    const float* __restrict__ ascore, const float* __restrict__ gw,
    const float* __restrict__ gb, float* __restrict__ out_alang,
    float* __restrict__ ws_film) {
    int b = blockIdx.x >> 2;
    int qd = blockIdx.x & 3;
    __shared__ float ms[NN];
    __shared__ float al[DD];
    int tid = threadIdx.x;
    if (tid == 0) {
        float s[NN];
        float mx = -1e30f;
        for (int n = 0; n < NN; ++n) { s[n] = ascore[b * NN + n] * TEMP_F; mx = fmaxf(mx, s[n]); }
        float se = 0.f;
        for (int n = 0; n < NN; ++n) { s[n] = expf(s[n] - mx); se += s[n]; }
        int m[NN]; int idx = 0;
        for (int n = 0; n < NN; ++n) m[n] = wmask[b * NN + n];
        m[0] = 0;
        for (int n = 0; n < NN; ++n) idx += m[n];
        m[idx] = 0;
        float tot = 0.f;
        for (int n = 0; n < NN; ++n) { float v = (s[n] / se) * (float)m[n]; ms[n] = v; tot += v; }
        float inv = 1.f / (tot + 1e-8f);
        for (int n = 0; n < NN; ++n) ms[n] *= inv;
    }
    __syncthreads();
    for (int d = tid; d < DD; d += 256) {
        float a = 0.f;
        #pragma unroll
        for (int n = 0; n < NN; ++n) a += ms[n] * fword[((size_t)b * NN + n) * DD + d];
        al[d] = a;
        if (qd == 0) out_alang[b * DD + d] = a;
    }
    __syncthreads();
    {
        int r = qd * 256 + tid;
        const float4* grow = (const float4*)(gw + (size_t)r * DD);
        const float4* av = (const float4*)al;
        float dot = 0.f;
        #pragma unroll 4
        for (int i = 0; i < DD / 4; ++i) {
            float4 g4 = grow[i]; float4 a4 = av[i];
            dot += g4.x * a4.x + g4.y * a4.y + g4.z * a4.z + g4.w * a4.w;
        }
        ws_film[b * 2 * EE + r] = tanhf(dot + gb[r]);
    }
}

// ---------------- Kernel C2: film GEMV, coalesced columns, grid BB*4 ----------------
__global__ __launch_bounds__(256) void k_film(
    const float* __restrict__ alang, const float* __restrict__ gwT,
    const float* __restrict__ gb, float* __restrict__ ws_film) {
    int b = blockIdx.x >> 2;
    int q = blockIdx.x & 3;
    __shared__ float al[DD];
    int t = threadIdx.x;
    al[t] = alang[b * DD + t];
    al[t + 256] = alang[b * DD + t + 256];
    __syncthreads();
    int r = q * 256 + t;
    float acc = 0.f;
    #pragma unroll 8
    for (int k = 0; k < DD; ++k)
        acc += al[k] * gwT[(size_t)k * 1024 + r];
    ws_film[b * 1024 + r] = tanhf(acc + gb[r]);
}

// ---------------- Kernel D: all-register MFMA GEMM (M=64) + IN + FiLM + residual ----------------
__global__ __launch_bounds__(512, 2) void k_gemm_in_film(
    const unsigned short* __restrict__ Xf, const unsigned short* __restrict__ Wf,
    const float* __restrict__ film, float* __restrict__ out) {
    __shared__ float sP[8][64];
    __shared__ float qP[8][64];
    __shared__ float st[64][4];    // mu, rs, gamma, beta
    int L = blockIdx.x;
    int ot = (L >> 3) & 7;                 // same-b blocks: L = c + 8*ot + 64*h
    int b  = (L >> 6) * 8 + (L & 7);       // -> same XCD (L%8 fixed), same round
    int t = threadIdx.x;
    int w = t >> 6, l = t & 63;

    const unsigned short* Xw = Xf + ((size_t)b * 64 + w * 8) * (KCN * 512) + (size_t)l * 8;
    const unsigned short* Wb = Wf + (size_t)(ot * 4) * (KCN * 512) + (size_t)l * 8;
    int ot2 = 2 * ot;

    f32x4 acc[4][8];
    #pragma unroll
    for (int m = 0; m < 4; ++m)
        #pragma unroll
        for (int n = 0; n < 8; ++n) acc[m][n] = (f32x4){0.f, 0.f, 0.f, 0.f};

    auto kcof = [&](int j) -> int {
        if (j < 15) return j + (j >= ot2 ? 2 : 0);
        return (j == 15) ? ot2 : (ot2 + 1);
    };
    auto loadB = [&](int j, bf16x8* bf_) {
        int kc = kcof(j);
        #pragma unroll
        for (int i = 0; i < 8; ++i)
            bf_[i] = *(const bf16x8*)(Xw + ((size_t)i * KCN + kc) * 512);
    };
    auto loadA = [&](int j, bf16x8* af) {
        int kc = kcof(j);
        #pragma unroll
        for (int m = 0; m < 4; ++m)
            af[m] = *(const bf16x8*)(Wb + ((size_t)m * KCN + kc) * 512);
    };
    auto compute = [&](const bf16x8* af, const bf16x8* bf_) {
        __builtin_amdgcn_s_setprio(1);
        #pragma unroll
        for (int m = 0; m < 4; ++m)
            #pragma unroll
            for (int n = 0; n < 8; ++n)
                acc[m][n] = __builtin_amdgcn_mfma_f32_16x16x32_bf16(af[m], bf_[n], acc[m][n], 0, 0, 0);
        __builtin_amdgcn_s_setprio(0);
    };

    bf16x8 bA[8], bB[8], aA[4], aB[4];
    loadB(0, bA);
    loadA(0, aA);

    #pragma unroll
    for (int j = 0; j < KCN; ++j) {
        if (j & 1) {
            if (j + 1 < KCN) { loadB(j + 1, bA); loadA(j + 1, aA); }
            compute(aB, bB);
        } else {
            if (j + 1 < KCN) { loadB(j + 1, bB); loadA(j + 1, aB); }
            compute(aA, bA);
        }
    }

    // ---- InstanceNorm stats ----
    #pragma unroll
    for (int m = 0; m < 4; ++m) {
        #pragma unroll
        for (int j = 0; j < 4; ++j) {
            float s = 0.f, q = 0.f;
            #pragma unroll
            for (int n = 0; n < 8; ++n) { float v = acc[m][n][j]; s += v; q += v * v; }
            #pragma unroll
            for (int off = 1; off < 16; off <<= 1) {
                s += __shfl_xor(s, off, 64);
                q += __shfl_xor(q, off, 64);
            }
            if ((l & 15) == 0) {
                int ol = m * 16 + (l >> 4) * 4 + j;
                sP[w][ol] = s;
                qP[w][ol] = q;
            }
        }
    }
    __syncthreads();
    if (t < 64) {
        float s = 0.f, q = 0.f;
        #pragma unroll
        for (int ww = 0; ww < 8; ++ww) { s += sP[ww][t]; q += qP[ww][t]; }
        float mu = s * (1.0f / HW);
        float var = q * (1.0f / HW) - mu * mu;
        int oc = ot * 64 + t;
        st[t][0] = mu;
        st[t][1] = rsqrtf(var + 1e-5f);
        st[t][2] = film[b * 1024 + oc];
        st[t][3] = film[b * 1024 + 512 + oc];
    }
    __syncthreads();

    // ---- apply norm + FiLM + ReLU + residual (bf16 from Xf, L2-hot), store ----
    float* ob = out + ((size_t)b * DD + ot * 64) * HW;
    int q4 = l >> 4;
    #pragma unroll
    for (int m = 0; m < 4; ++m) {
        int kc_m = ot2 + (m >> 1);
        int lp = ((m & 1) * 2 + (q4 >> 1)) * 16 + (l & 15);
        int uo = lp * 8 + (q4 & 1) * 4;   // ushort offset within fragment
        #pragma unroll
        for (int n = 0; n < 8; ++n) {
            ushort4 rb = *(const ushort4*)(Xf + ((size_t)b * 64 + w * 8 + n) * (KCN * 512)
                                           + ((size_t)kc_m) * 512 + uo);
            int px = w * 128 + n * 16 + (l & 15);
            #pragma unroll
            for (int jj = 0; jj < 4; ++jj) {
                int ol = m * 16 + q4 * 4 + jj;
                f32x4 sv = *(const f32x4*)&st[ol][0];
                float nrm = (acc[m][n][jj] - sv[0]) * sv[1];
                float rr = sv[2] * nrm + sv[3];
                rr = rr > 0.f ? rr : 0.f;
                float res = bf2f(((const unsigned short*)&rb)[jj]);
                ob[(size_t)ol * HW + px] = res + rr;
            }
        }
    }
}

// ---------------- Fallback (round-1 f32 path) ----------------
__global__ __launch_bounds__(256) void k_conv_in_film(
    const float* __restrict__ fvisu, const float* __restrict__ fcoord,
    const float* __restrict__ cw, const float* __restrict__ film,
    float* __restrict__ out) {
    int L = blockIdx.x;
    int b = L & 63;
    int tgt = L >> 6;
    int o0 = tgt * 16;
    int tid = threadIdx.x;
    __shared__ float xs[8][HW];
    __shared__ float red[16][4][2];
    __shared__ float stats[16][2];
    float acc[16][4];
    #pragma unroll
    for (int o = 0; o < 16; ++o)
        #pragma unroll
        for (int j = 0; j < 4; ++j) acc[o][j] = 0.f;

    const float* xb_v = fvisu + (size_t)b * DD * HW;
    const float* xb_c = fcoord + (size_t)b * 8 * HW;

    for (int c0 = 0; c0 < CIN; c0 += 8) {
        #pragma unroll
        for (int i = 0; i < 8; ++i) {
            int c = c0 + i;
            const float* src = (c < DD) ? (xb_v + (size_t)c * HW) : (xb_c + (size_t)(c - DD) * HW);
            ((float4*)xs[i])[tid] = ((const float4*)src)[tid];
        }
        __syncthreads();
        #pragma unroll
        for (int i = 0; i < 8; ++i) {
            float xv[4];
            #pragma unroll
            for (int j = 0; j < 4; ++j) xv[j] = xs[i][tid + 256 * j];
            #pragma unroll
            for (int o = 0; o < 16; ++o) {
                float wv = cw[(size_t)(o0 + o) * CIN + (c0 + i)];
                #pragma unroll
                for (int j = 0; j < 4; ++j) acc[o][j] = fmaf(wv, xv[j], acc[o][j]);
            }
        }
        __syncthreads();
    }
    int lane = tid & 63, wid = tid >> 6;
    #pragma unroll
    for (int o = 0; o < 16; ++o) {
        float s = 0.f, q = 0.f;
        #pragma unroll
        for (int j = 0; j < 4; ++j) { s += acc[o][j]; q += acc[o][j] * acc[o][j]; }
        #pragma unroll
        for (int off = 32; off; off >>= 1) {
            s += __shfl_down(s, off, 64);
            q += __shfl_down(q, off, 64);
        }
        if (lane == 0) { red[o][wid][0] = s; red[o][wid][1] = q; }
    }
    __syncthreads();
    if (tid < 16) {
        float s = red[tid][0][0] + red[tid][1][0] + red[tid][2][0] + red[tid][3][0];
        float q = red[tid][0][1] + red[tid][1][1] + red[tid][2][1] + red[tid][3][1];
        float mu = s * (1.0f / HW);
        float var = q * (1.0f / HW) - mu * mu;
        stats[tid][0] = mu;
        stats[tid][1] = rsqrtf(var + 1e-5f);
    }
    __syncthreads();
    #pragma unroll
    for (int o = 0; o < 16; ++o) {
        int oc = o0 + o;
        float mu = stats[o][0], rs = stats[o][1];
        float g  = film[b * 1024 + oc];
        float be = film[b * 1024 + 512 + oc];
        const float* fv = xb_v + (size_t)oc * HW;
        float* op = out + ((size_t)b * DD + oc) * HW;
        #pragma unroll
        for (int j = 0; j < 4; ++j) {
            int p = tid + 256 * j;
            float nrm = (acc[o][j] - mu) * rs;
            float rr = g * nrm + be;
            rr = rr > 0.f ? rr : 0.f;
            op[p] = fv[p] + rr;
        }
    }
}

extern "C" void kernel_launch(void* const* d_in, const int* in_sizes, int n_in,
                              void* d_out, int out_size, void* d_ws, size_t ws_size,
                              hipStream_t stream) {
    const float* fvisu  = (const float*)d_in[0];
    const float* fword  = (const float*)d_in[1];
    const float* cscore = (const float*)d_in[2];
    const float* fcoord = (const float*)d_in[3];
    // d_in[4] = gest (unused by reference)
    const int*   wmask  = (const int*)d_in[5];
    const float* amw    = (const float*)d_in[6];
    const float* amb    = (const float*)d_in[7];
    const float* asw    = (const float*)d_in[8];
    const float* asb    = (const float*)d_in[9];
    const float* gw     = (const float*)d_in[10];
    const float* gb     = (const float*)d_in[11];
    const float* cw     = (const float*)d_in[12];
    // d_in[13] = conv1_b: cancels in instance norm, unused

    float* out = (float*)d_out;
    float* ws_tv   = (float*)d_ws;                    // 32768 floats = 128 KB
    float* ws_film = ws_tv + BB * DD;                 // 65536 floats = 256 KB
    unsigned short* Xf  = (unsigned short*)((char*)d_ws + 393216);
    unsigned short* Wf  = (unsigned short*)((char*)d_ws + 393216 + 71303168);
    unsigned short* Whi = (unsigned short*)((char*)d_ws + 393216 + 71303168 + 557056);
    unsigned short* Wlo = Whi + 131072;               // each 256 KB
    float* gwT = (float*)((char*)d_ws + 393216 + 71303168 + 557056 + 524288);  // 2 MB
    const size_t need = 393216 + 71303168 + 557056 + 524288 + 2097152;

    float* out_alang  = out + OUT_ALANG;
    float* out_ascore = out + OUT_ASCORE;

    if (ws_size >= need) {
        k_convert_params<<<328, 256, 0, stream>>>(cw, Wf, amw, Whi, Wlo, gw, gwT);
        k_convert_x<<<BB * KCN, 512, 0, stream>>>(fvisu, fcoord, Xf, ws_tv);
        k_attnscore<<<BB, 256, 0, stream>>>(fword, cscore, ws_tv, Whi, Wlo, amb, asw, asb,
                                            wmask, out_ascore, out_alang);
        k_film<<<BB * 4, 256, 0, stream>>>(out_alang, gwT, gb, ws_film);
        k_gemm_in_film<<<512, 512, 0, stream>>>(Xf, Wf, ws_film, out);
    } else {
        k_tilevisu<<<BB * DD, 256, 0, stream>>>(fvisu, ws_tv);
        k_attnscore_legacy<<<BB * NN, 256, 0, stream>>>(fword, cscore, ws_tv, amw, amb, asw, asb, out_ascore);
        k_lang_film<<<BB * 4, 256, 0, stream>>>(fword, wmask, out_ascore, gw, gb, out_alang, ws_film);
        k_conv_in_film<<<BB * 32, 256, 0, stream>>>(fvisu, fcoord, cw, ws_film, out);
    }
}

// Round 13
// 175.416 us; speedup vs baseline: 4.1980x; 1.0008x over previous
//
#include <hip/hip_runtime.h>
#include <math.h>

#define BB 64
#define DD 512
#define HW 1024
#define NN 20
#define EE 512
#define CIN 520
#define KCN 17            // K chunks of 32 (K padded 520 -> 544)
#define TEMP_F 10.0f

#define OUT_ALANG (BB*DD*HW)            // 33554432
#define OUT_ASCORE (OUT_ALANG + BB*DD)  // 33587200

typedef __bf16 bf16x8 __attribute__((ext_vector_type(8)));
typedef float f32x4 __attribute__((ext_vector_type(4)));

__device__ __forceinline__ unsigned int pack2bf(float a, float b) {
    unsigned int ua = __builtin_bit_cast(unsigned int, a);
    unsigned int ub = __builtin_bit_cast(unsigned int, b);
    ua += 0x7fffu + ((ua >> 16) & 1u);   // RTNE
    ub += 0x7fffu + ((ub >> 16) & 1u);
    return (ua >> 16) | (ub & 0xffff0000u);
}

__device__ __forceinline__ unsigned short bfr(float x) {
    unsigned int u = __builtin_bit_cast(unsigned int, x);
    u += 0x7fffu + ((u >> 16) & 1u);
    return (unsigned short)(u >> 16);
}

__device__ __forceinline__ float bf2f(unsigned short u) {
    unsigned int x = ((unsigned int)u) << 16;
    return __builtin_bit_cast(float, x);
}

// ---------------- Kernel A (fallback only): tile_visu ----------------
__global__ __launch_bounds__(256) void k_tilevisu(const float* __restrict__ fvisu,
                                                  float* __restrict__ tv) {
    int row = blockIdx.x;
    const float4* p = (const float4*)(fvisu + (size_t)row * HW);
    int tid = threadIdx.x;
    float4 v = p[tid];
    float s = v.x + v.y + v.z + v.w;
    #pragma unroll
    for (int off = 32; off; off >>= 1) s += __shfl_down(s, off, 64);
    __shared__ float part[4];
    if ((tid & 63) == 0) part[tid >> 6] = s;
    __syncthreads();
    if (tid == 0) tv[row] = (part[0] + part[1] + part[2] + part[3]) * (1.0f / HW);
}

// ---------------- Kernel X1: fused tile_visu + pack X -> bf16 fragments ----------------
// LDS-staged stores: pack -> LDS frag[64][528] (padded), then contiguous 1KB stores.
__global__ __launch_bounds__(512, 2) void k_convert_x(
    const float* __restrict__ fvisu, const float* __restrict__ fcoord,
    unsigned short* __restrict__ Xf, float* __restrict__ tv) {
    __shared__ unsigned short frag[64][528];   // 67.6 KB (8-ushort row pad vs 512)
    __shared__ float red[8][8];
    int L = blockIdx.x;
    int kc = L % KCN;
    int b  = L / KCN;
    int t = threadIdx.x;
    int co = t >> 7;          // 0..3 (wave-uniform k-octet)
    int tl = t & 127;
    int cbase = kc * 32 + co * 8;
    float sums[8];
    #pragma unroll
    for (int j = 0; j < 8; ++j) sums[j] = 0.f;

    #pragma unroll
    for (int i = 0; i < 2; ++i) {
        int p0 = (tl + 128 * i) * 4;
        float4 f4[8];
        #pragma unroll
        for (int j = 0; j < 8; ++j) {
            int c = cbase + j;
            if (c < DD) {
                f4[j] = *(const float4*)&fvisu[((size_t)b * DD + c) * HW + p0];
            } else if (c < CIN) {
                f4[j] = *(const float4*)&fcoord[((size_t)b * 8 + (c - DD)) * HW + p0];
            } else {
                f4[j] = make_float4(0.f, 0.f, 0.f, 0.f);
            }
        }
        #pragma unroll
        for (int j = 0; j < 8; ++j)
            if (cbase + j < DD) sums[j] += f4[j].x + f4[j].y + f4[j].z + f4[j].w;

        int P = p0 >> 4;
        #pragma unroll
        for (int i2 = 0; i2 < 4; ++i2) {
            uint4 v;
            v.x = pack2bf(((const float*)&f4[0])[i2], ((const float*)&f4[1])[i2]);
            v.y = pack2bf(((const float*)&f4[2])[i2], ((const float*)&f4[3])[i2]);
            v.z = pack2bf(((const float*)&f4[4])[i2], ((const float*)&f4[5])[i2]);
            v.w = pack2bf(((const float*)&f4[6])[i2], ((const float*)&f4[7])[i2]);
            int unit = co * 16 + (p0 & 15) + i2;   // fragment 16B-unit index
            *(uint4*)&frag[P][unit * 8] = v;
        }
    }

    // tv channel-mean partials
    #pragma unroll
    for (int j = 0; j < 8; ++j) {
        float s = sums[j];
        #pragma unroll
        for (int off = 32; off; off >>= 1) s += __shfl_down(s, off, 64);
        sums[j] = s;
    }
    int w = t >> 6, l = t & 63;
    if (l == 0) {
        #pragma unroll
        for (int j = 0; j < 8; ++j) red[w][j] = sums[j];
    }
    __syncthreads();

    // coalesced fragment stores — 1KB contiguous per wave-instruction
    #pragma unroll
    for (int fi = 0; fi < 8; ++fi) {
        int f = w * 8 + fi;
        uint4 v = *(const uint4*)&frag[f][l * 8];
        *(uint4*)&Xf[(((size_t)b * 64 + f) * KCN + kc) * 512 + (size_t)l * 8] = v;
    }

    if (t < 32) {
        int j = t & 7, c2 = t >> 3;
        int c = kc * 32 + c2 * 8 + j;
        if (c < DD) tv[(size_t)b * DD + c] = (red[c2 * 2][j] + red[c2 * 2 + 1][j]) * (1.0f / HW);
    }
}

// ---------------- Kernel X2: merged param converts (Wf | Whi/Wlo | gwT) ----------------
__global__ __launch_bounds__(256) void k_convert_params(
    const float* __restrict__ cw, unsigned short* __restrict__ Wf,
    const float* __restrict__ amw, unsigned short* __restrict__ Whi,
    unsigned short* __restrict__ Wlo,
    const float* __restrict__ gw, float* __restrict__ gwT) {
    int B0 = blockIdx.x;
    int t = threadIdx.x;
    if (B0 < 136) {
        int frag = B0 * 4 + (t >> 6);   // 0..543
        int l = t & 63;
        int M = frag / KCN, kc = frag % KCN;
        int o = M * 16 + (l & 15);
        int k0 = kc * 32 + (l >> 4) * 8;
        float f[8];
        #pragma unroll
        for (int j = 0; j < 8; ++j) {
            int k = k0 + j;
            f[j] = (k < CIN) ? cw[(size_t)o * CIN + k] : 0.f;
        }
        uint4 v;
        v.x = pack2bf(f[0], f[1]);
        v.y = pack2bf(f[2], f[3]);
        v.z = pack2bf(f[4], f[5]);
        v.w = pack2bf(f[6], f[7]);
        *(uint4*)&Wf[(size_t)frag * 512 + (size_t)l * 8] = v;
    } else if (B0 < 200) {
        int fid = (B0 - 136) * 4 + (t >> 6);    // 0..255
        int l = t & 63;
        int o = (fid >> 4) * 16 + (l & 15);
        int k0 = (fid & 15) * 32 + ((l >> 4) & 3) * 8;
        float hi[8], lo[8];
        #pragma unroll
        for (int j = 0; j < 8; ++j) {
            float x = amw[(size_t)o * DD + k0 + j];
            unsigned short h = bfr(x);
            hi[j] = bf2f(h);
            lo[j] = x - hi[j];
        }
        uint4 vh, vl;
        vh.x = pack2bf(hi[0], hi[1]); vh.y = pack2bf(hi[2], hi[3]);
        vh.z = pack2bf(hi[4], hi[5]); vh.w = pack2bf(hi[6], hi[7]);
        vl.x = pack2bf(lo[0], lo[1]); vl.y = pack2bf(lo[2], lo[3]);
        vl.z = pack2bf(lo[4], lo[5]); vl.w = pack2bf(lo[6], lo[7]);
        *(uint4*)&Whi[(size_t)fid * 512 + (size_t)l * 8] = vh;
        *(uint4*)&Wlo[(size_t)fid * 512 + (size_t)l * 8] = vl;
    } else {
        __shared__ float tile[64][65];
        int bt = B0 - 200;
        int rt = bt & 15, kt = bt >> 4;
        int rl = t >> 4;            // 0..15
        int kl = (t & 15) * 4;      // 0..60
        #pragma unroll
        for (int i = 0; i < 4; ++i) {
            int rr = rl + i * 16;
            float4 v = *(const float4*)&gw[(size_t)(rt * 64 + rr) * DD + kt * 64 + kl];
            tile[rr][kl + 0] = v.x; tile[rr][kl + 1] = v.y;
            tile[rr][kl + 2] = v.z; tile[rr][kl + 3] = v.w;
        }
        __syncthreads();
        #pragma unroll
        for (int i = 0; i < 4; ++i) {
            int kk = rl + i * 16;
            float4 v;
            v.x = tile[kl + 0][kk]; v.y = tile[kl + 1][kk];
            v.z = tile[kl + 2][kk]; v.w = tile[kl + 3][kk];
            *(float4*)&gwT[(size_t)(kt * 64 + kk) * 1024 + rt * 64 + kl] = v;
        }
    }
}

// ---------------- Kernel B: attn_score via MFMA hi/lo + fused softmax/mask + attn_lang ----------------
__global__ __launch_bounds__(256) void k_attnscore(
    const float* __restrict__ fword, const float* __restrict__ cs,
    const float* __restrict__ tv, const unsigned short* __restrict__ Whi,
    const unsigned short* __restrict__ Wlo, const float* __restrict__ amb,
    const float* __restrict__ asw, const float* __restrict__ asb,
    const int* __restrict__ wmask, float* __restrict__ out_ascore,
    float* __restrict__ out_alang) {
    int b = blockIdx.x;
    __shared__ unsigned short uhi[2][16][64][8];   // 32 KB: [mt][ks][lane][j]
    __shared__ unsigned short ulo[2][16][64][8];   // 32 KB
    __shared__ float scoreP[4][32];
    __shared__ float asc_sh[NN];
    __shared__ float msh[NN];
    int t = threadIdx.x;

    {
        int n = t & 31, kq = t >> 5;               // kq: k-range of 64
        float csv = (n < NN) ? cs[b * NN + n] : 0.f;
        const float* fwp = fword + ((size_t)b * NN + (n < NN ? n : 0)) * DD;
        const float* tvp = tv + (size_t)b * DD;
        int mt = n >> 4;
        #pragma unroll
        for (int oc = 0; oc < 8; ++oc) {
            int k = kq * 64 + oc * 8;
            float x[8];
            if (n < NN) {
                float4 f0 = *(const float4*)&fwp[k];
                float4 f1 = *(const float4*)&fwp[k + 4];
                float4 t0 = *(const float4*)&tvp[k];
                float4 t1 = *(const float4*)&tvp[k + 4];
                x[0] = f0.x * t0.x * csv; x[1] = f0.y * t0.y * csv;
                x[2] = f0.z * t0.z * csv; x[3] = f0.w * t0.w * csv;
                x[4] = f1.x * t1.x * csv; x[5] = f1.y * t1.y * csv;
                x[6] = f1.z * t1.z * csv; x[7] = f1.w * t1.w * csv;
            } else {
                #pragma unroll
                for (int j = 0; j < 8; ++j) x[j] = 0.f;
            }
            float h[8], lw[8];
            #pragma unroll
            for (int j = 0; j < 8; ++j) {
                h[j] = bf2f(bfr(x[j]));
                lw[j] = x[j] - h[j];
            }
            int ks = k >> 5;
            int l = (n & 15) + ((k >> 3) & 3) * 16;
            uint4 vh, vl;
            vh.x = pack2bf(h[0], h[1]); vh.y = pack2bf(h[2], h[3]);
            vh.z = pack2bf(h[4], h[5]); vh.w = pack2bf(h[6], h[7]);
            vl.x = pack2bf(lw[0], lw[1]); vl.y = pack2bf(lw[2], lw[3]);
            vl.z = pack2bf(lw[4], lw[5]); vl.w = pack2bf(lw[6], lw[7]);
            *(uint4*)&uhi[mt][ks][l][0] = vh;
            *(uint4*)&ulo[mt][ks][l][0] = vl;
        }
    }
    __syncthreads();

    int w = t >> 6, l = t & 63;
    f32x4 acc[2][4];
    #pragma unroll
    for (int mt = 0; mt < 2; ++mt)
        #pragma unroll
        for (int nt = 0; nt < 4; ++nt) acc[mt][nt] = (f32x4){0.f, 0.f, 0.f, 0.f};

    #pragma unroll 4
    for (int ks = 0; ks < 16; ++ks) {
        bf16x8 ah0 = *(const bf16x8*)&uhi[0][ks][l][0];
        bf16x8 ah1 = *(const bf16x8*)&uhi[1][ks][l][0];
        bf16x8 al0 = *(const bf16x8*)&ulo[0][ks][l][0];
        bf16x8 al1 = *(const bf16x8*)&ulo[1][ks][l][0];
        #pragma unroll
        for (int nt = 0; nt < 4; ++nt) {
            size_t fo = ((size_t)((w * 4 + nt) * 16 + ks)) * 512 + (size_t)l * 8;
            bf16x8 bh = *(const bf16x8*)&Whi[fo];
            bf16x8 bl = *(const bf16x8*)&Wlo[fo];
            acc[0][nt] = __builtin_amdgcn_mfma_f32_16x16x32_bf16(ah0, bh, acc[0][nt], 0, 0, 0);
            acc[0][nt] = __builtin_amdgcn_mfma_f32_16x16x32_bf16(al0, bh, acc[0][nt], 0, 0, 0);
            acc[0][nt] = __builtin_amdgcn_mfma_f32_16x16x32_bf16(ah0, bl, acc[0][nt], 0, 0, 0);
            acc[1][nt] = __builtin_amdgcn_mfma_f32_16x16x32_bf16(ah1, bh, acc[1][nt], 0, 0, 0);
            acc[1][nt] = __builtin_amdgcn_mfma_f32_16x16x32_bf16(al1, bh, acc[1][nt], 0, 0, 0);
            acc[1][nt] = __builtin_amdgcn_mfma_f32_16x16x32_bf16(ah1, bl, acc[1][nt], 0, 0, 0);
        }
    }

    float ambv[4], aswv[4];
    #pragma unroll
    for (int nt = 0; nt < 4; ++nt) {
        int o = (w * 4 + nt) * 16 + (l & 15);
        ambv[nt] = amb[o];
        aswv[nt] = asw[o];
    }
    #pragma unroll
    for (int mt = 0; mt < 2; ++mt) {
        #pragma unroll
        for (int j = 0; j < 4; ++j) {
            float p = 0.f;
            #pragma unroll
            for (int nt = 0; nt < 4; ++nt)
                p += aswv[nt] * tanhf(acc[mt][nt][j] + ambv[nt]);
            #pragma unroll
            for (int off = 1; off < 16; off <<= 1) p += __shfl_xor(p, off, 64);
            if ((l & 15) == 0) scoreP[w][mt * 16 + (l >> 4) * 4 + j] = p;
        }
    }
    __syncthreads();
    if (t < NN) {
        float v = scoreP[0][t] + scoreP[1][t] + scoreP[2][t] + scoreP[3][t] + asb[0];
        out_ascore[b * NN + t] = v;
        asc_sh[t] = v;
    }
    __syncthreads();

    if (t == 0) {
        float s[NN];
        float mx = -1e30f;
        for (int n = 0; n < NN; ++n) { s[n] = asc_sh[n] * TEMP_F; mx = fmaxf(mx, s[n]); }
        float se = 0.f;
        for (int n = 0; n < NN; ++n) { s[n] = expf(s[n] - mx); se += s[n]; }
        int m[NN]; int idx = 0;
        for (int n = 0; n < NN; ++n) m[n] = wmask[b * NN + n];
        m[0] = 0;
        for (int n = 0; n < NN; ++n) idx += m[n];
        m[idx] = 0;
        float tot = 0.f;
        for (int n = 0; n < NN; ++n) { float v = (s[n] / se) * (float)m[n]; msh[n] = v; tot += v; }
        float inv = 1.f / (tot + 1e-8f);
        for (int n = 0; n < NN; ++n) msh[n] *= inv;
    }
    __syncthreads();

    #pragma unroll 2
    for (int d = t; d < DD; d += 256) {
        float a = 0.f;
        #pragma unroll
        for (int n = 0; n < NN; ++n) a += msh[n] * fword[((size_t)b * NN + n) * DD + d];
        out_alang[b * DD + d] = a;
    }
}

// ---------------- Kernel B-legacy (fallback only) ----------------
__global__ __launch_bounds__(256) void k_attnscore_legacy(
    const float* __restrict__ fword, const float* __restrict__ cs,
    const float* __restrict__ tv, const float* __restrict__ amw,
    const float* __restrict__ amb, const float* __restrict__ asw,
    const float* __restrict__ asb, float* __restrict__ out_ascore) {
    int bn = blockIdx.x;
    int b = bn / NN, n = bn % NN;
    __shared__ float u[DD];
    __shared__ float part[4];
    int tid = threadIdx.x;
    float csv = cs[b * NN + n];
    for (int d = tid; d < DD; d += 256)
        u[d] = tv[b * DD + d] * fword[((size_t)b * NN + n) * DD + d] * csv;
    __syncthreads();
    int o = tid;
    const float4* wrow = (const float4*)(amw + (size_t)o * DD);
    const float4* uv = (const float4*)u;
    float dot = 0.f;
    #pragma unroll 4
    for (int i = 0; i < DD / 4; ++i) {
        float4 w4 = wrow[i]; float4 u4 = uv[i];
        dot += w4.x * u4.x + w4.y * u4.y + w4.z * u4.z + w4.w * u4.w;
    }
    float contrib = asw[o] * tanhf(dot + amb[o]);
    #pragma unroll
    for (int off = 32; off; off >>= 1) contrib += __shfl_down(contrib, off, 64);
    if ((tid & 63) == 0) part[tid >> 6] = contrib;
    __syncthreads();
    if (tid == 0) out_ascore[b * NN + n] = part[0] + part[1] + part[2] + part[3] + asb[0];
}

// ---------------- Kernel C (fallback only): mask_softmax + attn_lang + FiLM decode ----------------
__global__ __launch_bounds__(256) void k_lang_film(
    const float* __restrict__ fword, const int* __restrict__ wmask,
    const float* __restrict__ ascore, const float* __restrict__ gw,
    const float* __restrict__ gb, float* __restrict__ out_alang,
    float* __restrict__ ws_film) {
    int b = blockIdx.x >> 2;
    int qd = blockIdx.x & 3;
    __shared__ float ms[NN];
    __shared__ float al[DD];
    int tid = threadIdx.x;
    if (tid == 0) {
        float s[NN];
        float mx = -1e30f;
        for (int n = 0; n < NN; ++n) { s[n] = ascore[b * NN + n] * TEMP_F; mx = fmaxf(mx, s[n]); }
        float se = 0.f;
        for (int n = 0; n < NN; ++n) { s[n] = expf(s[n] - mx); se += s[n]; }
        int m[NN]; int idx = 0;
        for (int n = 0; n < NN; ++n) m[n] = wmask[b * NN + n];
        m[0] = 0;
        for (int n = 0; n < NN; ++n) idx += m[n];
        m[idx] = 0;
        float tot = 0.f;
        for (int n = 0; n < NN; ++n) { float v = (s[n] / se) * (float)m[n]; ms[n] = v; tot += v; }
        float inv = 1.f / (tot + 1e-8f);
        for (int n = 0; n < NN; ++n) ms[n] *= inv;
    }
    __syncthreads();
    for (int d = tid; d < DD; d += 256) {
        float a = 0.f;
        #pragma unroll
        for (int n = 0; n < NN; ++n) a += ms[n] * fword[((size_t)b * NN + n) * DD + d];
        al[d] = a;
        if (qd == 0) out_alang[b * DD + d] = a;
    }
    __syncthreads();
    {
        int r = qd * 256 + tid;
        const float4* grow = (const float4*)(gw + (size_t)r * DD);
        const float4* av = (const float4*)al;
        float dot = 0.f;
        #pragma unroll 4
        for (int i = 0; i < DD / 4; ++i) {
            float4 g4 = grow[i]; float4 a4 = av[i];
            dot += g4.x * a4.x + g4.y * a4.y + g4.z * a4.z + g4.w * a4.w;
        }
        ws_film[b * 2 * EE + r] = tanhf(dot + gb[r]);
    }
}

// ---------------- Kernel C2: film GEMV, coalesced columns, grid BB*4 ----------------
__global__ __launch_bounds__(256) void k_film(
    const float* __restrict__ alang, const float* __restrict__ gwT,
    const float* __restrict__ gb, float* __restrict__ ws_film) {
    int b = blockIdx.x >> 2;
    int q = blockIdx.x & 3;
    __shared__ float al[DD];
    int t = threadIdx.x;
    al[t] = alang[b * DD + t];
    al[t + 256] = alang[b * DD + t + 256];
    __syncthreads();
    int r = q * 256 + t;
    float acc = 0.f;
    #pragma unroll 8
    for (int k = 0; k < DD; ++k)
        acc += al[k] * gwT[(size_t)k * 1024 + r];
    ws_film[b * 1024 + r] = tanhf(acc + gb[r]);
}

// ---------------- Kernel D: MFMA GEMM, A-in-LDS + triple-buffered B + IN + FiLM + residual ----------------
// grid 512: block (b, ot) = 64 o-chans x 1024 px, 8 waves, wave tile 64x128.
// A (Wf, 68 frags = 68KB) staged to LDS once (1 barrier); K-loop barrier-free.
// B triple-buffered in VGPRs, prefetch 2 chunks ahead (16 loads in flight).
// VGPR budget: acc 128 + B 96 + A-transient 4 + addr ~15 = ~245 < 256 (2 waves/SIMD).
__global__ __launch_bounds__(512, 2) void k_gemm_in_film(
    const unsigned short* __restrict__ Xf, const unsigned short* __restrict__ Wf,
    const float* __restrict__ film, float* __restrict__ out) {
    __shared__ __align__(16) unsigned short als[68 * 512];   // 68 KB: A fragments [m*KCN+kc][lane][8]
    __shared__ float sP[8][64];
    __shared__ float qP[8][64];
    __shared__ float st[64][4];    // mu, rs, gamma, beta
    int L = blockIdx.x;
    int ot = (L >> 3) & 7;                 // same-b blocks: L = c + 8*ot + 64*h
    int b  = (L >> 6) * 8 + (L & 7);       // -> same XCD (L%8 fixed), same round
    int t = threadIdx.x;
    int w = t >> 6, l = t & 63;

    const unsigned short* Xw = Xf + ((size_t)b * 64 + w * 8) * (KCN * 512) + (size_t)l * 8;
    int ot2 = 2 * ot;

    f32x4 acc[4][8];
    #pragma unroll
    for (int m = 0; m < 4; ++m)
        #pragma unroll
        for (int n = 0; n < 8; ++n) acc[m][n] = (f32x4){0.f, 0.f, 0.f, 0.f};

    auto kcof = [&](int j) -> int {
        if (j < 15) return j + (j >= ot2 ? 2 : 0);
        return (j == 15) ? ot2 : (ot2 + 1);
    };
    auto loadB = [&](int j, bf16x8* bf_) {
        int kc = kcof(j);
        #pragma unroll
        for (int i = 0; i < 8; ++i)
            bf_[i] = *(const bf16x8*)(Xw + ((size_t)i * KCN + kc) * 512);
    };
    auto compute = [&](int j, const bf16x8* bf_) {
        int kc = kcof(j);
        __builtin_amdgcn_s_setprio(1);
        #pragma unroll
        for (int m = 0; m < 4; ++m) {
            bf16x8 a = *(const bf16x8*)&als[(size_t)((m * KCN + kc) * 64 + l) * 8];
            #pragma unroll
            for (int n = 0; n < 8; ++n)
                acc[m][n] = __builtin_amdgcn_mfma_f32_16x16x32_bf16(a, bf_[n], acc[m][n], 0, 0, 0);
        }
        __builtin_amdgcn_s_setprio(0);
    };

    bf16x8 b0[8], b1[8], b2[8];
    loadB(0, b0);
    loadB(1, b1);

    // stage all A fragments (this block's 68 contiguous frags of Wf) into LDS
    {
        const unsigned short* Wbase = Wf + (size_t)(ot * 68) * 512;
        #pragma unroll
        for (int i = 0; i < 9; ++i) {
            int idx = t + i * 512;
            if (idx < 68 * 64)
                *(uint4*)&als[(size_t)idx * 8] = *(const uint4*)&Wbase[(size_t)idx * 8];
        }
    }
    __syncthreads();

    #pragma unroll
    for (int j = 0; j < KCN; ++j) {
        bf16x8* cur = (j % 3 == 0) ? b0 : (j % 3 == 1) ? b1 : b2;
        if (j + 2 < KCN) {
            bf16x8* nxt = ((j + 2) % 3 == 0) ? b0 : ((j + 2) % 3 == 1) ? b1 : b2;
            loadB(j + 2, nxt);
        }
        compute(j, cur);
    }

    // ---- InstanceNorm stats ----
    #pragma unroll
    for (int m = 0; m < 4; ++m) {
        #pragma unroll
        for (int j = 0; j < 4; ++j) {
            float s = 0.f, q = 0.f;
            #pragma unroll
            for (int n = 0; n < 8; ++n) { float v = acc[m][n][j]; s += v; q += v * v; }
            #pragma unroll
            for (int off = 1; off < 16; off <<= 1) {
                s += __shfl_xor(s, off, 64);
                q += __shfl_xor(q, off, 64);
            }
            if ((l & 15) == 0) {
                int ol = m * 16 + (l >> 4) * 4 + j;
                sP[w][ol] = s;
                qP[w][ol] = q;
            }
        }
    }
    __syncthreads();
    if (t < 64) {
        float s = 0.f, q = 0.f;
        #pragma unroll
        for (int ww = 0; ww < 8; ++ww) { s += sP[ww][t]; q += qP[ww][t]; }
        float mu = s * (1.0f / HW);
        float var = q * (1.0f / HW) - mu * mu;
        int oc = ot * 64 + t;
        st[t][0] = mu;
        st[t][1] = rsqrtf(var + 1e-5f);
        st[t][2] = film[b * 1024 + oc];
        st[t][3] = film[b * 1024 + 512 + oc];
    }
    __syncthreads();

    // ---- apply norm + FiLM + ReLU + residual (bf16 from Xf, L2-hot), store ----
    float* ob = out + ((size_t)b * DD + ot * 64) * HW;
    int q4 = l >> 4;
    #pragma unroll
    for (int m = 0; m < 4; ++m) {
        int kc_m = ot2 + (m >> 1);
        int lp = ((m & 1) * 2 + (q4 >> 1)) * 16 + (l & 15);
        int uo = lp * 8 + (q4 & 1) * 4;   // ushort offset within fragment
        #pragma unroll
        for (int n = 0; n < 8; ++n) {
            ushort4 rb = *(const ushort4*)(Xf + ((size_t)b * 64 + w * 8 + n) * (KCN * 512)
                                           + ((size_t)kc_m) * 512 + uo);
            int px = w * 128 + n * 16 + (l & 15);
            #pragma unroll
            for (int jj = 0; jj < 4; ++jj) {
                int ol = m * 16 + q4 * 4 + jj;
                f32x4 sv = *(const f32x4*)&st[ol][0];
                float nrm = (acc[m][n][jj] - sv[0]) * sv[1];
                float rr = sv[2] * nrm + sv[3];
                rr = rr > 0.f ? rr : 0.f;
                float res = bf2f(((const unsigned short*)&rb)[jj]);
                ob[(size_t)ol * HW + px] = res + rr;
            }
        }
    }
}

// ---------------- Fallback (round-1 f32 path) ----------------
__global__ __launch_bounds__(256) void k_conv_in_film(
    const float* __restrict__ fvisu, const float* __restrict__ fcoord,
    const float* __restrict__ cw, const float* __restrict__ film,
    float* __restrict__ out) {
    int L = blockIdx.x;
    int b = L & 63;
    int tgt = L >> 6;
    int o0 = tgt * 16;
    int tid = threadIdx.x;
    __shared__ float xs[8][HW];
    __shared__ float red[16][4][2];
    __shared__ float stats[16][2];
    float acc[16][4];
    #pragma unroll
    for (int o = 0; o < 16; ++o)
        #pragma unroll
        for (int j = 0; j < 4; ++j) acc[o][j] = 0.f;

    const float* xb_v = fvisu + (size_t)b * DD * HW;
    const float* xb_c = fcoord + (size_t)b * 8 * HW;

    for (int c0 = 0; c0 < CIN; c0 += 8) {
        #pragma unroll
        for (int i = 0; i < 8; ++i) {
            int c = c0 + i;
            const float* src = (c < DD) ? (xb_v + (size_t)c * HW) : (xb_c + (size_t)(c - DD) * HW);
            ((float4*)xs[i])[tid] = ((const float4*)src)[tid];
        }
        __syncthreads();
        #pragma unroll
        for (int i = 0; i < 8; ++i) {
            float xv[4];
            #pragma unroll
            for (int j = 0; j < 4; ++j) xv[j] = xs[i][tid + 256 * j];
            #pragma unroll
            for (int o = 0; o < 16; ++o) {
                float wv = cw[(size_t)(o0 + o) * CIN + (c0 + i)];
                #pragma unroll
                for (int j = 0; j < 4; ++j) acc[o][j] = fmaf(wv, xv[j], acc[o][j]);
            }
        }
        __syncthreads();
    }
    int lane = tid & 63, wid = tid >> 6;
    #pragma unroll
    for (int o = 0; o < 16; ++o) {
        float s = 0.f, q = 0.f;
        #pragma unroll
        for (int j = 0; j < 4; ++j) { s += acc[o][j]; q += acc[o][j] * acc[o][j]; }
        #pragma unroll
        for (int off = 32; off; off >>= 1) {
            s += __shfl_down(s, off, 64);
            q += __shfl_down(q, off, 64);
        }
        if (lane == 0) { red[o][wid][0] = s; red[o][wid][1] = q; }
    }
    __syncthreads();
    if (tid < 16) {
        float s = red[tid][0][0] + red[tid][1][0] + red[tid][2][0] + red[tid][3][0];
        float q = red[tid][0][1] + red[tid][1][1] + red[tid][2][1] + red[tid][3][1];
        float mu = s * (1.0f / HW);
        float var = q * (1.0f / HW) - mu * mu;
        stats[tid][0] = mu;
        stats[tid][1] = rsqrtf(var + 1e-5f);
    }
    __syncthreads();
    #pragma unroll
    for (int o = 0; o < 16; ++o) {
        int oc = o0 + o;
        float mu = stats[o][0], rs = stats[o][1];
        float g  = film[b * 1024 + oc];
        float be = film[b * 1024 + 512 + oc];
        const float* fv = xb_v + (size_t)oc * HW;
        float* op = out + ((size_t)b * DD + oc) * HW;
        #pragma unroll
        for (int j = 0; j < 4; ++j) {
            int p = tid + 256 * j;
            float nrm = (acc[o][j] - mu) * rs;
            float rr = g * nrm + be;
            rr = rr > 0.f ? rr : 0.f;
            op[p] = fv[p] + rr;
        }
    }
}

extern "C" void kernel_launch(void* const* d_in, const int* in_sizes, int n_in,
                              void* d_out, int out_size, void* d_ws, size_t ws_size,
                              hipStream_t stream) {
    const float* fvisu  = (const float*)d_in[0];
    const float* fword  = (const float*)d_in[1];
    const float* cscore = (const float*)d_in[2];
    const float* fcoord = (const float*)d_in[3];
    // d_in[4] = gest (unused by reference)
    const int*   wmask  = (const int*)d_in[5];
    const float* amw    = (const float*)d_in[6];
    const float* amb    = (const float*)d_in[7];
    const float* asw    = (const float*)d_in[8];
    const float* asb    = (const float*)d_in[9];
    const float* gw     = (const float*)d_in[10];
    const float* gb     = (const float*)d_in[11];
    const float* cw     = (const float*)d_in[12];
    // d_in[13] = conv1_b: cancels in instance norm, unused

    float* out = (float*)d_out;
    float* ws_tv   = (float*)d_ws;                    // 32768 floats = 128 KB
    float* ws_film = ws_tv + BB * DD;                 // 65536 floats = 256 KB
    unsigned short* Xf  = (unsigned short*)((char*)d_ws + 393216);
    unsigned short* Wf  = (unsigned short*)((char*)d_ws + 393216 + 71303168);
    unsigned short* Whi = (unsigned short*)((char*)d_ws + 393216 + 71303168 + 557056);
    unsigned short* Wlo = Whi + 131072;               // each 256 KB
    float* gwT = (float*)((char*)d_ws + 393216 + 71303168 + 557056 + 524288);  // 2 MB
    const size_t need = 393216 + 71303168 + 557056 + 524288 + 2097152;

    float* out_alang  = out + OUT_ALANG;
    float* out_ascore = out + OUT_ASCORE;

    if (ws_size >= need) {
        k_convert_params<<<328, 256, 0, stream>>>(cw, Wf, amw, Whi, Wlo, gw, gwT);
        k_convert_x<<<BB * KCN, 512, 0, stream>>>(fvisu, fcoord, Xf, ws_tv);
        k_attnscore<<<BB, 256, 0, stream>>>(fword, cscore, ws_tv, Whi, Wlo, amb, asw, asb,
                                            wmask, out_ascore, out_alang);
        k_film<<<BB * 4, 256, 0, stream>>>(out_alang, gwT, gb, ws_film);
        k_gemm_in_film<<<512, 512, 0, stream>>>(Xf, Wf, ws_film, out);
    } else {
        k_tilevisu<<<BB * DD, 256, 0, stream>>>(fvisu, ws_tv);
        k_attnscore_legacy<<<BB * NN, 256, 0, stream>>>(fword, cscore, ws_tv, amw, amb, asw, asb, out_ascore);
        k_lang_film<<<BB * 4, 256, 0, stream>>>(fword, wmask, out_ascore, gw, gb, out_alang, ws_film);
        k_conv_in_film<<<BB * 32, 256, 0, stream>>>(fvisu, fcoord, cw, ws_film, out);
    }
}